// Round 7
// baseline (568.604 us; speedup 1.0000x reference)
//
#include <hip/hip_runtime.h>
#include <hip/hip_bf16.h>

#define NN 50000
#define NE 1200000
#define DIN 128
#define HDIM 64
#define NG 64
#define EPSV 1e-5f

__device__ __forceinline__ float b2f(const __hip_bfloat16 v) { return __bfloat162float(v); }
__device__ __forceinline__ float bu2f(unsigned short u) {
    unsigned int x = ((unsigned int)u) << 16;
    return __uint_as_float(x);
}
__device__ __forceinline__ unsigned short f2bu(float f) {
    __hip_bfloat16 b = __float2bfloat16(f);
    return *(unsigned short*)&b;
}

__device__ __forceinline__ float ldf(const void* p, size_t idx, int isbf16) {
    return isbf16 ? b2f(((const __hip_bfloat16*)p)[idx]) : ((const float*)p)[idx];
}

// ---------------- dtype detection ----------------
__global__ void k_detect(const unsigned short* __restrict__ x, int* __restrict__ cnt, int n) {
    int i = blockIdx.x * 256 + threadIdx.x;
    if (i < n) {
        unsigned short u = x[i];
        if (((u >> 7) & 0xFF) == 0xFF) atomicAdd(cnt, 1);
    }
}

// flag = 1 if bf16, 0 if fp32
__global__ void k_resolve(const int* __restrict__ cnt, int* __restrict__ flag) {
    if (threadIdx.x == 0 && blockIdx.x == 0) *flag = (*cnt < 4) ? 1 : 0;
}

// ---------------- param conversion into fp32 workspace ----------------
#define PW_WIN   0
#define PW_BIN   8192
#define PW_GCNW  8256
#define PW_GCNB  16448
#define PW_GCNBN 16576
#define PW_SWL   17088
#define PW_SWR   25280
#define PW_SB    33472
#define PW_SBN   33600
#define PW_F1W   34112
#define PW_F1B   42304
#define PW_BN1   42368
#define PW_F2W   42624
#define PW_F2B   44672
#define PW_BN2   44704
#define PW_F3W   44832
#define PW_F3B   44864
#define PW_TOT   44865

struct PSrc { const void* p[17]; };

__global__ void k_cvt(PSrc s, const int* __restrict__ flag, float* __restrict__ dst) {
    const int offs[18] = {PW_WIN, PW_BIN, PW_GCNW, PW_GCNB, PW_GCNBN, PW_SWL, PW_SWR,
                          PW_SB, PW_SBN, PW_F1W, PW_F1B, PW_BN1, PW_F2W, PW_F2B,
                          PW_BN2, PW_F3W, PW_F3B, PW_TOT};
    int i = blockIdx.x * 256 + threadIdx.x;
    if (i >= PW_TOT) return;
    int f = *flag;
    int seg = 0;
    while (i >= offs[seg + 1]) ++seg;
    dst[i] = ldf(s.p[seg], i - offs[seg], f);
}

// ---------------- CSR build ----------------
__global__ void k_degree(const int* __restrict__ dst, int* __restrict__ indeg,
                         int* __restrict__ rank, int E) {
    int e = blockIdx.x * 256 + threadIdx.x;
    if (e < E) rank[e] = atomicAdd(&indeg[dst[e]], 1);
}

__global__ __launch_bounds__(256) void k_gcount(const int* __restrict__ batch,
                                                int* __restrict__ gcnt, int n) {
    __shared__ int hist[NG];
    int t = threadIdx.x;
    if (t < NG) hist[t] = 0;
    __syncthreads();
    int v = blockIdx.x * 1024 + t;
#pragma unroll
    for (int j = 0; j < 4; ++j, v += 256)
        if (v < n) atomicAdd(&hist[batch[v]], 1);
    __syncthreads();
    if (t < NG) {
        int c = hist[t];
        if (c) atomicAdd(&gcnt[t], c);
    }
}

__global__ __launch_bounds__(1024) void k_scan(const int* __restrict__ indeg,
                                               int* __restrict__ rowptr,
                                               float* __restrict__ dinv,
                                               float* __restrict__ cinv, int n) {
    __shared__ int wsum[16];
    __shared__ int carry_s;
    int t = threadIdx.x;
    int wid = t >> 6, lane = t & 63;
    if (t == 0) carry_s = 0;
    __syncthreads();
    for (int base = 0; base < n; base += 1024) {
        int i = base + t;
        int d = (i < n) ? indeg[i] : 0;
        if (i < n) {
            float fd = (float)d;
            dinv[i] = rsqrtf(fd + 1.0f);
            cinv[i] = 1.0f / fmaxf(fd, 1.0f);
        }
        int x = d;
#pragma unroll
        for (int off = 1; off < 64; off <<= 1) {
            int y = __shfl_up(x, off, 64);
            if (lane >= off) x += y;
        }
        if (lane == 63) wsum[wid] = x;
        __syncthreads();
        if (wid == 0) {
            int s = (lane < 16) ? wsum[lane] : 0;
#pragma unroll
            for (int off = 1; off < 16; off <<= 1) {
                int y = __shfl_up(s, off, 64);
                if (lane >= off) s += y;
            }
            if (lane < 16) wsum[lane] = s;
        }
        __syncthreads();
        int waveoff = (wid > 0) ? wsum[wid - 1] : 0;
        int incl = carry_s + waveoff + x;
        if (i < n) rowptr[i] = incl - d;
        __syncthreads();
        if (t == 1023) carry_s = incl;
        __syncthreads();
    }
    if (t == 0) rowptr[n] = carry_s;
}

__global__ void k_fill(const int* __restrict__ src, const int* __restrict__ dst,
                       const int* __restrict__ rowptr, const int* __restrict__ rank,
                       int* __restrict__ csr_src, int E) {
    int e = blockIdx.x * 256 + threadIdx.x;
    if (e < E) {
        int d = dst[e];
        csr_src[rowptr[d] + rank[e]] = src[e];
    }
}

// ---------------- GEMM helpers ----------------
__device__ __forceinline__ void mac16(float acc[4][4], const float4 av, const float4 wv) {
    float a[4] = {av.x, av.y, av.z, av.w};
    float w[4] = {wv.x, wv.y, wv.z, wv.w};
#pragma unroll
    for (int i = 0; i < 4; i++)
#pragma unroll
        for (int j = 0; j < 4; j++) acc[i][j] = fmaf(a[i], w[j], acc[i][j]);
}

// h = relu(x @ W_in + b_in); writes fp32 h and bf16 shadow hb
__global__ __launch_bounds__(256) void k_in_gemm(const void* __restrict__ A,
                                                 const float* __restrict__ W,
                                                 const float* __restrict__ bias,
                                                 const int* __restrict__ flag,
                                                 float* __restrict__ out,
                                                 unsigned short* __restrict__ outb, int n) {
    __shared__ float As[64][68];
    __shared__ float Ws[64][64];
    int t = threadIdx.x;
    int v0 = blockIdx.x * 64;
    int tx = t & 15, ty = t >> 4;
    int f16 = *flag;
    float acc[4][4] = {};
    for (int k0 = 0; k0 < 128; k0 += 64) {
#pragma unroll
        for (int j = 0; j < 16; ++j) {
            int i = t + 256 * j;
            int r = i >> 6, k = i & 63;
            int v = v0 + r;
            As[k][r] = (v < n) ? ldf(A, (size_t)v * DIN + k0 + k, f16) : 0.0f;
        }
#pragma unroll
        for (int j = 0; j < 16; ++j) {
            int i = t + 256 * j;
            Ws[i >> 6][i & 63] = W[(size_t)(k0 + (i >> 6)) * 64 + (i & 63)];
        }
        __syncthreads();
#pragma unroll 8
        for (int k = 0; k < 64; ++k) {
            float4 wv = *(const float4*)&Ws[k][tx * 4];
            float4 av = *(const float4*)&As[k][ty * 4];
            mac16(acc, av, wv);
        }
        __syncthreads();
    }
#pragma unroll
    for (int i = 0; i < 4; i++) {
        int v = v0 + ty * 4 + i;
        if (v < n) {
#pragma unroll
            for (int j = 0; j < 4; j++) {
                int f = tx * 4 + j;
                float y = fmaxf(acc[i][j] + bias[f], 0.0f);
                out[(size_t)v * 64 + f] = y;
                outb[(size_t)v * 64 + f] = f2bu(y);
            }
        }
    }
}

// Fused per-layer GEMM; out fp32 interleaved; outb (optional) bf16 interleaved shadow.
__global__ __launch_bounds__(256) void k_layer_gemm(
        const float* __restrict__ g, const float* __restrict__ self,
        int selfStride, int selfOff, int selfStep,
        const float* __restrict__ W0, const float* __restrict__ Wl,
        const float* __restrict__ Wr,
        const float* __restrict__ b0, const float* __restrict__ bs,
        const float* __restrict__ bn0, const float* __restrict__ bns,
        float* __restrict__ out, unsigned int* __restrict__ outb, int n) {
    __shared__ float Ag[64][68];
    __shared__ float Asg[64][68];
    __shared__ float Wa[64][64];
    __shared__ float Wb[64][64];
    int t = threadIdx.x;
    int v0 = blockIdx.x * 64;
    int tx = t & 15, ty = t >> 4;
    float accg[4][4] = {};
    float accs[4][4] = {};
#pragma unroll
    for (int j = 0; j < 16; ++j) {
        int i = t + 256 * j;
        int r = i >> 6, k = i & 63;
        int v = v0 + r;
        float2 val = make_float2(0.0f, 0.0f);
        if (v < n) val = *(const float2*)&g[(size_t)v * 128 + 2 * k];
        Ag[k][r] = val.x;
        Asg[k][r] = val.y;
        Wa[i >> 6][i & 63] = W0[i];
        Wb[i >> 6][i & 63] = Wl[i];
    }
    __syncthreads();
#pragma unroll 4
    for (int k = 0; k < 64; ++k) {
        float4 w0 = *(const float4*)&Wa[k][tx * 4];
        float4 wl = *(const float4*)&Wb[k][tx * 4];
        float4 ag = *(const float4*)&Ag[k][ty * 4];
        float4 as = *(const float4*)&Asg[k][ty * 4];
        mac16(accg, ag, w0);
        mac16(accs, as, wl);
    }
    __syncthreads();
#pragma unroll
    for (int j = 0; j < 16; ++j) {
        int i = t + 256 * j;
        int r = i >> 6, k = i & 63;
        int v = v0 + r;
        Ag[k][r] = (v < n) ? self[(size_t)v * selfStride + selfOff + k * selfStep] : 0.0f;
        Wa[i >> 6][i & 63] = Wr[i];
    }
    __syncthreads();
#pragma unroll 4
    for (int k = 0; k < 64; ++k) {
        float4 wr = *(const float4*)&Wa[k][tx * 4];
        float4 av = *(const float4*)&Ag[k][ty * 4];
        mac16(accs, av, wr);
    }
#pragma unroll
    for (int i = 0; i < 4; i++) {
        int v = v0 + ty * 4 + i;
        if (v < n) {
#pragma unroll
            for (int j = 0; j < 4; j++) {
                int f = tx * 4 + j;
                float yg = accg[i][j] + b0[f];
                yg = (yg - bn0[128 + f]) * rsqrtf(bn0[192 + f] + EPSV) * bn0[f] + bn0[64 + f];
                float ys = accs[i][j] + bs[f];
                ys = (ys - bns[128 + f]) * rsqrtf(bns[192 + f] + EPSV) * bns[f] + bns[64 + f];
                yg = fmaxf(yg, 0.0f);
                ys = fmaxf(ys, 0.0f);
                *(float2*)&out[(size_t)v * 128 + 2 * f] = make_float2(yg, ys);
                if (outb) {
                    unsigned int pk = (unsigned int)f2bu(yg) | ((unsigned int)f2bu(ys) << 16);
                    outb[(size_t)v * 64 + f] = pk;
                }
            }
        }
    }
}

// ---------------- fused dual gathers on bf16 shadows (1 wave = 1 node) ----------------
// L0: hb rows (128B each); GCN-normalized sum + SAGE sum in one pass.
__global__ __launch_bounds__(256) void k_gather0(const unsigned short* __restrict__ hb,
                                                 const float* __restrict__ dinv,
                                                 const float* __restrict__ cinv,
                                                 const int* __restrict__ rowptr,
                                                 const int* __restrict__ csr_src,
                                                 float* __restrict__ g, int n) {
    int wid = threadIdx.x >> 6, lane = threadIdx.x & 63;
    int v = blockIdx.x * 4 + wid;
    if (v >= n) return;
    int beg = rowptr[v], end = rowptr[v + 1];
    float accg = 0.0f, accs = 0.0f;
    int i = beg;
    for (; i + 8 <= end; i += 8) {
        int s[8];
#pragma unroll
        for (int j = 0; j < 8; ++j) s[j] = csr_src[i + j];
        float x[8], w[8];
#pragma unroll
        for (int j = 0; j < 8; ++j) x[j] = bu2f(hb[(size_t)s[j] * 64 + lane]);
#pragma unroll
        for (int j = 0; j < 8; ++j) w[j] = dinv[s[j]];
#pragma unroll
        for (int j = 0; j < 8; ++j) { accg = fmaf(x[j], w[j], accg); accs += x[j]; }
    }
    for (; i < end; ++i) {
        int s = csr_src[i];
        float x = bu2f(hb[(size_t)s * 64 + lane]);
        accg = fmaf(x, dinv[s], accg);
        accs += x;
    }
    float dv = dinv[v];
    float yg = dv * (accg + dv * bu2f(hb[(size_t)v * 64 + lane]));
    float ys = cinv[v] * accs;
    *(float2*)&g[(size_t)v * 128 + 2 * lane] = make_float2(yg, ys);
}

// L1: bf16 interleaved rows (256B each); uint = (gcn | sage<<16) per lane.
__global__ __launch_bounds__(256) void k_gather1(const unsigned int* __restrict__ Cb,
                                                 const float* __restrict__ dinv,
                                                 const float* __restrict__ cinv,
                                                 const int* __restrict__ rowptr,
                                                 const int* __restrict__ csr_src,
                                                 float* __restrict__ g, int n) {
    int wid = threadIdx.x >> 6, lane = threadIdx.x & 63;
    int v = blockIdx.x * 4 + wid;
    if (v >= n) return;
    int beg = rowptr[v], end = rowptr[v + 1];
    float accg = 0.0f, accs = 0.0f;
    int i = beg;
    for (; i + 8 <= end; i += 8) {
        int s[8];
#pragma unroll
        for (int j = 0; j < 8; ++j) s[j] = csr_src[i + j];
        unsigned int u[8];
#pragma unroll
        for (int j = 0; j < 8; ++j) u[j] = Cb[(size_t)s[j] * 64 + lane];
        float w[8];
#pragma unroll
        for (int j = 0; j < 8; ++j) w[j] = dinv[s[j]];
#pragma unroll
        for (int j = 0; j < 8; ++j) {
            float xg = bu2f((unsigned short)(u[j] & 0xFFFF));
            float xs = bu2f((unsigned short)(u[j] >> 16));
            accg = fmaf(xg, w[j], accg);
            accs += xs;
        }
    }
    for (; i < end; ++i) {
        int s = csr_src[i];
        unsigned int u = Cb[(size_t)s * 64 + lane];
        accg = fmaf(bu2f((unsigned short)(u & 0xFFFF)), dinv[s], accg);
        accs += bu2f((unsigned short)(u >> 16));
    }
    float dv = dinv[v];
    unsigned int us = Cb[(size_t)v * 64 + lane];
    float yg = dv * (accg + dv * bu2f((unsigned short)(us & 0xFFFF)));
    float ys = cinv[v] * accs;
    *(float2*)&g[(size_t)v * 128 + 2 * lane] = make_float2(yg, ys);
}

// ---------------- pooling over interleaved final feats ----------------
__global__ __launch_bounds__(256) void k_pool2(const float* __restrict__ X2,
                                               const int* __restrict__ batch,
                                               float* __restrict__ pooled, int n) {
    int wid = threadIdx.x >> 6, lane = threadIdx.x & 63;
    int v0 = blockIdx.x * 64 + wid * 16;
    float ag = 0.0f, as = 0.0f;
    int g = -1;
    for (int j = 0; j < 16; ++j) {
        int v = v0 + j;
        if (v >= n) break;
        int b = batch[v];
        if (b != g) {
            if (g >= 0) {
                atomicAdd(&pooled[g * 128 + lane], ag);
                atomicAdd(&pooled[g * 128 + 64 + lane], as);
            }
            g = b; ag = 0.0f; as = 0.0f;
        }
        float2 val = *(const float2*)&X2[(size_t)v * 128 + 2 * lane];
        ag += val.x; as += val.y;
    }
    if (g >= 0) {
        atomicAdd(&pooled[g * 128 + lane], ag);
        atomicAdd(&pooled[g * 128 + 64 + lane], as);
    }
}

// ---------------- head MLP (single block) ----------------
__global__ __launch_bounds__(256) void k_head(const float* __restrict__ pooled,
                                              const int* __restrict__ gcnt,
                                              const float* __restrict__ P_,
                                              const int* __restrict__ flag,
                                              void* __restrict__ out) {
    const float* f1W = P_ + PW_F1W;
    const float* f1b = P_ + PW_F1B;
    const float* bn1 = P_ + PW_BN1;
    const float* f2W = P_ + PW_F2W;
    const float* f2b = P_ + PW_F2B;
    const float* bn2 = P_ + PW_BN2;
    const float* f3W = P_ + PW_F3W;
    const float* f3b = P_ + PW_F3B;
    __shared__ float P[64][128];
    __shared__ float Z1[64][64];
    __shared__ float Z2[64][32];
    int t = threadIdx.x;
    for (int i = t; i < 64 * 128; i += 256) {
        int g = i >> 7;
        float c = fmaxf((float)gcnt[g], 1.0f);
        P[g][i & 127] = pooled[i] / c;
    }
    __syncthreads();
    for (int o = t; o < 64 * 64; o += 256) {
        int g = o >> 6, f = o & 63;
        float acc = 0.0f;
        for (int c = 0; c < 128; ++c) acc = fmaf(P[g][c], f1W[c * 64 + f], acc);
        float y = acc + f1b[f];
        y = (y - bn1[128 + f]) * rsqrtf(bn1[192 + f] + EPSV) * bn1[f] + bn1[64 + f];
        Z1[g][f] = fmaxf(y, 0.0f);
    }
    __syncthreads();
    for (int o = t; o < 64 * 32; o += 256) {
        int g = o >> 5, f = o & 31;
        float acc = 0.0f;
        for (int c = 0; c < 64; ++c) acc = fmaf(Z1[g][c], f2W[c * 32 + f], acc);
        float y = acc + f2b[f];
        y = (y - bn2[64 + f]) * rsqrtf(bn2[96 + f] + EPSV) * bn2[f] + bn2[32 + f];
        Z2[g][f] = fmaxf(y, 0.0f);
    }
    __syncthreads();
    if (t < 64) {
        float acc = 0.0f;
        for (int c = 0; c < 32; ++c) acc = fmaf(Z2[t][c], f3W[c], acc);
        float y = acc + f3b[0];
        if (*flag) ((__hip_bfloat16*)out)[t] = __float2bfloat16(y);
        else       ((float*)out)[t] = y;
    }
}

extern "C" void kernel_launch(void* const* d_in, const int* in_sizes, int n_in,
                              void* d_out, int out_size, void* d_ws, size_t ws_size,
                              hipStream_t stream) {
    (void)in_sizes; (void)n_in; (void)out_size; (void)ws_size;
    const void* x     = d_in[0];
    const int*  eidx  = (const int*)d_in[1];
    const int*  batch = (const int*)d_in[2];

    const int n = NN, E = NE;
    const int* src = eidx;
    const int* dst = eidx + E;

    char* w = (char*)d_ws;
    float* h   = (float*)w;  w += (size_t)n * 64 * 4;     // [n][64] fp32
    unsigned short* hb = (unsigned short*)w; w += (size_t)n * 64 * 2;   // bf16 shadow
    float* g   = (float*)w;  w += (size_t)n * 128 * 4;    // gather out, interleaved fp32
    float* C1  = (float*)w;  w += (size_t)n * 128 * 4;    // layer-0 out fp32 interleaved
    unsigned int* C1b = (unsigned int*)w; w += (size_t)n * 64 * 4;  // bf16x2 shadow
    float* C2  = (float*)w;  w += (size_t)n * 128 * 4;    // layer-1 out fp32 interleaved
    int*   indeg  = (int*)w;  w += (size_t)n * 4;
    int*   rowptr = (int*)w;  w += (size_t)(n + 8) * 4;
    int*   rank   = (int*)w;  w += (size_t)E * 4;
    int*   csr_src = (int*)w; w += (size_t)E * 4;
    float* dinv  = (float*)w; w += (size_t)n * 4;
    float* cinv  = (float*)w; w += (size_t)n * 4;
    int*   gcnt  = (int*)w;  w += 64 * 4;
    float* pooled = (float*)w; w += 64 * 128 * 4;
    int*   cnt   = (int*)w;  w += 8;
    int*   flag  = (int*)w;  w += 8;
    float* prm   = (float*)w;                  // PW_TOT floats

    hipMemsetAsync(indeg, 0, (size_t)n * 4, stream);
    hipMemsetAsync(gcnt, 0, 64 * 4 + 64 * 128 * 4, stream);  // gcnt + pooled contiguous
    hipMemsetAsync(cnt, 0, 4, stream);

    dim3 b256(256);

    const int DETN = 262144;
    k_detect<<<dim3(DETN / 256), b256, 0, stream>>>((const unsigned short*)x, cnt, DETN);
    k_resolve<<<1, 64, 0, stream>>>(cnt, flag);
    PSrc ps;
    for (int i = 0; i < 17; ++i) ps.p[i] = d_in[3 + i];
    k_cvt<<<dim3((PW_TOT + 255) / 256), b256, 0, stream>>>(ps, flag, prm);

    // CSR build (rank trick: no atomics in fill)
    k_degree<<<dim3((E + 255) / 256), b256, 0, stream>>>(dst, indeg, rank, E);
    k_scan<<<1, 1024, 0, stream>>>(indeg, rowptr, dinv, cinv, n);
    k_fill<<<dim3((E + 255) / 256), b256, 0, stream>>>(src, dst, rowptr, rank, csr_src, E);
    k_gcount<<<dim3((n + 1023) / 1024), b256, 0, stream>>>(batch, gcnt, n);

    int gGemm = (n + 63) / 64;
    int gGath = (n + 3) / 4;
    int gPool = (n + 63) / 64;

    k_in_gemm<<<gGemm, b256, 0, stream>>>(x, prm + PW_WIN, prm + PW_BIN, flag, h, hb, n);

    // layer 0: dual gather (bf16 h) -> g ; fused GEMMs -> C1 + C1b (self from fp32 h)
    k_gather0<<<gGath, b256, 0, stream>>>(hb, dinv, cinv, rowptr, csr_src, g, n);
    k_layer_gemm<<<gGemm, b256, 0, stream>>>(g, h, 64, 0, 1,
        prm + PW_GCNW, prm + PW_SWL, prm + PW_SWR,
        prm + PW_GCNB, prm + PW_SB, prm + PW_GCNBN, prm + PW_SBN, C1, C1b, n);

    // layer 1: dual gather (bf16 C1) -> g ; fused GEMMs -> C2 (self = C1 fp32 sage half)
    k_gather1<<<gGath, b256, 0, stream>>>(C1b, dinv, cinv, rowptr, csr_src, g, n);
    k_layer_gemm<<<gGemm, b256, 0, stream>>>(g, C1, 128, 1, 2,
        prm + PW_GCNW + 4096, prm + PW_SWL + 4096, prm + PW_SWR + 4096,
        prm + PW_GCNB + 64, prm + PW_SB + 64, prm + PW_GCNBN + 256, prm + PW_SBN + 256,
        C2, (unsigned int*)nullptr, n);

    // pooling (both halves) + head
    k_pool2<<<gPool, b256, 0, stream>>>(C2, batch, pooled, n);
    k_head<<<1, b256, 0, stream>>>(pooled, gcnt, prm, flag, d_out);
}

// Round 8
// 447.205 us; speedup vs baseline: 1.2715x; 1.2715x over previous
//
#include <hip/hip_runtime.h>
#include <hip/hip_bf16.h>

#define NN 50000
#define NE 1200000
#define DIN 128
#define HDIM 64
#define NG 64
#define EPSV 1e-5f

typedef __attribute__((ext_vector_type(8))) short bfrag;   // 8 bf16 = 4 VGPRs
typedef __attribute__((ext_vector_type(4))) float ffrag;   // 4 fp32 acc

__device__ __forceinline__ float b2f(const __hip_bfloat16 v) { return __bfloat162float(v); }
__device__ __forceinline__ float bu2f(unsigned short u) {
    return __uint_as_float(((unsigned int)u) << 16);
}
__device__ __forceinline__ unsigned short f2bu(float f) {
    __hip_bfloat16 b = __float2bfloat16(f);
    return *(unsigned short*)&b;
}
__device__ __forceinline__ unsigned int packbf(float a, float b) {
    return (unsigned int)f2bu(a) | ((unsigned int)f2bu(b) << 16);
}

__device__ __forceinline__ float ldf(const void* p, size_t idx, int isbf16) {
    return isbf16 ? b2f(((const __hip_bfloat16*)p)[idx]) : ((const float*)p)[idx];
}

// ---------------- dtype detection ----------------
__global__ void k_detect(const unsigned short* __restrict__ x, int* __restrict__ cnt, int n) {
    int i = blockIdx.x * 256 + threadIdx.x;
    if (i < n) {
        unsigned short u = x[i];
        if (((u >> 7) & 0xFF) == 0xFF) atomicAdd(cnt, 1);
    }
}

__global__ void k_resolve(const int* __restrict__ cnt, int* __restrict__ flag) {
    if (threadIdx.x == 0 && blockIdx.x == 0) *flag = (*cnt < 4) ? 1 : 0;
}

// ---------------- param conversion into fp32 workspace ----------------
#define PW_WIN   0
#define PW_BIN   8192
#define PW_GCNW  8256
#define PW_GCNB  16448
#define PW_GCNBN 16576
#define PW_SWL   17088
#define PW_SWR   25280
#define PW_SB    33472
#define PW_SBN   33600
#define PW_F1W   34112
#define PW_F1B   42304
#define PW_BN1   42368
#define PW_F2W   42624
#define PW_F2B   44672
#define PW_BN2   44704
#define PW_F3W   44832
#define PW_F3B   44864
#define PW_TOT   44865

struct PSrc { const void* p[17]; };

__global__ void k_cvt(PSrc s, const int* __restrict__ flag, float* __restrict__ dst) {
    const int offs[18] = {PW_WIN, PW_BIN, PW_GCNW, PW_GCNB, PW_GCNBN, PW_SWL, PW_SWR,
                          PW_SB, PW_SBN, PW_F1W, PW_F1B, PW_BN1, PW_F2W, PW_F2B,
                          PW_BN2, PW_F3W, PW_F3B, PW_TOT};
    int i = blockIdx.x * 256 + threadIdx.x;
    if (i >= PW_TOT) return;
    int f = *flag;
    int seg = 0;
    while (i >= offs[seg + 1]) ++seg;
    dst[i] = ldf(s.p[seg], i - offs[seg], f);
}

// bf16-transposed weights for MFMA B-operand: wt[mtx][n][k] = W[k][n]
__global__ void k_wprep(const float* __restrict__ prm, unsigned short* __restrict__ wt) {
    const int srcoff[6] = {PW_GCNW, PW_SWL, PW_SWR, PW_GCNW + 4096, PW_SWL + 4096, PW_SWR + 4096};
    int i = blockIdx.x * 256 + threadIdx.x;
    if (i >= 6 * 4096) return;
    int mtx = i >> 12, idx = i & 4095;
    int nn = idx >> 6, kk = idx & 63;
    wt[i] = f2bu(prm[srcoff[mtx] + kk * 64 + nn]);
}

// ---------------- CSR build ----------------
__global__ void k_degree(const int* __restrict__ dst, int* __restrict__ indeg,
                         int* __restrict__ rank, int E) {
    int e = blockIdx.x * 256 + threadIdx.x;
    if (e < E) rank[e] = atomicAdd(&indeg[dst[e]], 1);
}

__global__ __launch_bounds__(256) void k_gcount(const int* __restrict__ batch,
                                                int* __restrict__ gcnt, int n) {
    __shared__ int hist[NG];
    int t = threadIdx.x;
    if (t < NG) hist[t] = 0;
    __syncthreads();
    int v = blockIdx.x * 1024 + t;
#pragma unroll
    for (int j = 0; j < 4; ++j, v += 256)
        if (v < n) atomicAdd(&hist[batch[v]], 1);
    __syncthreads();
    if (t < NG) {
        int c = hist[t];
        if (c) atomicAdd(&gcnt[t], c);
    }
}

__global__ __launch_bounds__(1024) void k_scan(const int* __restrict__ indeg,
                                               int* __restrict__ rowptr,
                                               float* __restrict__ dinv,
                                               float* __restrict__ cinv, int n) {
    __shared__ int wsum[16];
    __shared__ int carry_s;
    int t = threadIdx.x;
    int wid = t >> 6, lane = t & 63;
    if (t == 0) carry_s = 0;
    __syncthreads();
    for (int base = 0; base < n; base += 1024) {
        int i = base + t;
        int d = (i < n) ? indeg[i] : 0;
        if (i < n) {
            float fd = (float)d;
            dinv[i] = rsqrtf(fd + 1.0f);
            cinv[i] = 1.0f / fmaxf(fd, 1.0f);
        }
        int x = d;
#pragma unroll
        for (int off = 1; off < 64; off <<= 1) {
            int y = __shfl_up(x, off, 64);
            if (lane >= off) x += y;
        }
        if (lane == 63) wsum[wid] = x;
        __syncthreads();
        if (wid == 0) {
            int s = (lane < 16) ? wsum[lane] : 0;
#pragma unroll
            for (int off = 1; off < 16; off <<= 1) {
                int y = __shfl_up(s, off, 64);
                if (lane >= off) s += y;
            }
            if (lane < 16) wsum[lane] = s;
        }
        __syncthreads();
        int waveoff = (wid > 0) ? wsum[wid - 1] : 0;
        int incl = carry_s + waveoff + x;
        if (i < n) rowptr[i] = incl - d;
        __syncthreads();
        if (t == 1023) carry_s = incl;
        __syncthreads();
    }
    if (t == 0) rowptr[n] = carry_s;
}

__global__ void k_fill(const int* __restrict__ src, const int* __restrict__ dst,
                       const int* __restrict__ rowptr, const int* __restrict__ rank,
                       int* __restrict__ csr_src, int E) {
    int e = blockIdx.x * 256 + threadIdx.x;
    if (e < E) {
        int d = dst[e];
        csr_src[rowptr[d] + rank[e]] = src[e];
    }
}

// ---------------- vector GEMM helper (input layer only) ----------------
__device__ __forceinline__ void mac16(float acc[4][4], const float4 av, const float4 wv) {
    float a[4] = {av.x, av.y, av.z, av.w};
    float w[4] = {wv.x, wv.y, wv.z, wv.w};
#pragma unroll
    for (int i = 0; i < 4; i++)
#pragma unroll
        for (int j = 0; j < 4; j++) acc[i][j] = fmaf(a[i], w[j], acc[i][j]);
}

// hb = bf16(relu(x @ W_in + b_in))
__global__ __launch_bounds__(256) void k_in_gemm(const void* __restrict__ A,
                                                 const float* __restrict__ W,
                                                 const float* __restrict__ bias,
                                                 const int* __restrict__ flag,
                                                 unsigned short* __restrict__ outb, int n) {
    __shared__ float As[64][68];
    __shared__ float Ws[64][64];
    int t = threadIdx.x;
    int v0 = blockIdx.x * 64;
    int tx = t & 15, ty = t >> 4;
    int f16 = *flag;
    float acc[4][4] = {};
    for (int k0 = 0; k0 < 128; k0 += 64) {
#pragma unroll
        for (int j = 0; j < 16; ++j) {
            int i = t + 256 * j;
            int r = i >> 6, k = i & 63;
            int v = v0 + r;
            As[k][r] = (v < n) ? ldf(A, (size_t)v * DIN + k0 + k, f16) : 0.0f;
        }
#pragma unroll
        for (int j = 0; j < 16; ++j) {
            int i = t + 256 * j;
            Ws[i >> 6][i & 63] = W[(size_t)(k0 + (i >> 6)) * 64 + (i & 63)];
        }
        __syncthreads();
#pragma unroll 8
        for (int k = 0; k < 64; ++k) {
            float4 wv = *(const float4*)&Ws[k][tx * 4];
            float4 av = *(const float4*)&As[k][ty * 4];
            mac16(acc, av, wv);
        }
        __syncthreads();
    }
#pragma unroll
    for (int i = 0; i < 4; i++) {
        int v = v0 + ty * 4 + i;
        if (v < n) {
#pragma unroll
            for (int j = 0; j < 4; j++) {
                int f = tx * 4 + j;
                outb[(size_t)v * 64 + f] = f2bu(fmaxf(acc[i][j] + bias[f], 0.0f));
            }
        }
    }
}

// ---------------- MFMA fused layer GEMM ----------------
// out_gcn  = relu(bn0( A_gcn @ W0 + b0 ))        A from gb (packed lo16)
// out_sage = relu(bns( A_sage @ Wl + self @ Wr + bs ))
// selfPacked=0: selfp = ushort[n][64] (hb). selfPacked=1: selfp = uint[n][64] (hi16=sage).
__global__ __launch_bounds__(256) void k_layer_mfma(
        const unsigned int* __restrict__ gb, const void* __restrict__ selfp, int selfPacked,
        const unsigned short* __restrict__ W0t, const unsigned short* __restrict__ Wlt,
        const unsigned short* __restrict__ Wrt,
        const float* __restrict__ b0, const float* __restrict__ bs,
        const float* __restrict__ bn0, const float* __restrict__ bns,
        float* __restrict__ outf, unsigned int* __restrict__ outp, int n) {
    __shared__ unsigned int Ag[64][68];            // packed (gcn|sage) tile
    __shared__ unsigned int Su[64][68];            // self tile (packed or raw ushorts)
    __shared__ unsigned short Wt0[64][72];
    __shared__ unsigned short Wt1[64][72];
    int t = threadIdx.x;
    int v0 = blockIdx.x * 64;

    // stage A tile (64 rows x 16 uint4)
    uint4 z4 = make_uint4(0, 0, 0, 0);
#pragma unroll
    for (int j = 0; j < 4; ++j) {
        int c = t + 256 * j;
        int r = c >> 4, cq = c & 15;
        int v = v0 + r;
        uint4 val = (v < n) ? *(const uint4*)&gb[(size_t)v * 64 + cq * 4] : z4;
        *(uint4*)&Ag[r][cq * 4] = val;
    }
    // stage self tile
    if (selfPacked) {
        const unsigned int* sp = (const unsigned int*)selfp;
#pragma unroll
        for (int j = 0; j < 4; ++j) {
            int c = t + 256 * j;
            int r = c >> 4, cq = c & 15;
            int v = v0 + r;
            uint4 val = (v < n) ? *(const uint4*)&sp[(size_t)v * 64 + cq * 4] : z4;
            *(uint4*)&Su[r][cq * 4] = val;
        }
    } else {
        const unsigned int* sp = (const unsigned int*)selfp;  // ushort rows as 32 uints
#pragma unroll
        for (int j = 0; j < 2; ++j) {
            int c = t + 256 * j;
            int r = c >> 3, cq = c & 7;
            int v = v0 + r;
            uint4 val = (v < n) ? *(const uint4*)&sp[(size_t)v * 32 + cq * 4] : z4;
            *(uint4*)&Su[r][cq * 4] = val;
        }
    }
    // stage W0t, Wlt (64 rows x 8 chunks of 8 bf16)
#pragma unroll
    for (int j = 0; j < 2; ++j) {
        int c = t + 256 * j;
        int r = c >> 3, cq = c & 7;
        *(uint4*)&Wt0[r][cq * 8] = *(const uint4*)&W0t[r * 64 + cq * 8];
        *(uint4*)&Wt1[r][cq * 8] = *(const uint4*)&Wlt[r * 64 + cq * 8];
    }
    __syncthreads();

    int w = t >> 6, lane = t & 63;
    int m = lane & 15, kq = lane >> 4;
    int lr = w * 16 + m;

    // A fragments (held in regs across all phases)
    bfrag ag[2], as_[2], asl[2];
#pragma unroll
    for (int s = 0; s < 2; ++s) {
        uint4 u0 = *(const uint4*)&Ag[lr][s * 32 + kq * 8];
        uint4 u1 = *(const uint4*)&Ag[lr][s * 32 + kq * 8 + 4];
        unsigned int uu[8] = {u0.x, u0.y, u0.z, u0.w, u1.x, u1.y, u1.z, u1.w};
#pragma unroll
        for (int j = 0; j < 8; ++j) {
            ag[s][j] = (short)(uu[j] & 0xFFFF);
            as_[s][j] = (short)(uu[j] >> 16);
        }
        if (selfPacked) {
            uint4 s0 = *(const uint4*)&Su[lr][s * 32 + kq * 8];
            uint4 s1 = *(const uint4*)&Su[lr][s * 32 + kq * 8 + 4];
            unsigned int su[8] = {s0.x, s0.y, s0.z, s0.w, s1.x, s1.y, s1.z, s1.w};
#pragma unroll
            for (int j = 0; j < 8; ++j) asl[s][j] = (short)(su[j] >> 16);
        } else {
            const unsigned short* srow = (const unsigned short*)&Su[lr][0];
            asl[s] = *(const bfrag*)(srow + s * 32 + kq * 8);
        }
    }

    ffrag zf = {0.0f, 0.0f, 0.0f, 0.0f};
    ffrag accg[4] = {zf, zf, zf, zf};
    ffrag accs[4] = {zf, zf, zf, zf};
#pragma unroll
    for (int nt = 0; nt < 4; ++nt) {
#pragma unroll
        for (int s = 0; s < 2; ++s) {
            bfrag b0f = *(const bfrag*)&Wt0[nt * 16 + m][s * 32 + kq * 8];
            accg[nt] = __builtin_amdgcn_mfma_f32_16x16x32_bf16(ag[s], b0f, accg[nt], 0, 0, 0);
            bfrag b1f = *(const bfrag*)&Wt1[nt * 16 + m][s * 32 + kq * 8];
            accs[nt] = __builtin_amdgcn_mfma_f32_16x16x32_bf16(as_[s], b1f, accs[nt], 0, 0, 0);
        }
    }
    __syncthreads();
    // restage Wt0 = Wrt
#pragma unroll
    for (int j = 0; j < 2; ++j) {
        int c = t + 256 * j;
        int r = c >> 3, cq = c & 7;
        *(uint4*)&Wt0[r][cq * 8] = *(const uint4*)&Wrt[r * 64 + cq * 8];
    }
    __syncthreads();
#pragma unroll
    for (int nt = 0; nt < 4; ++nt) {
#pragma unroll
        for (int s = 0; s < 2; ++s) {
            bfrag brf = *(const bfrag*)&Wt0[nt * 16 + m][s * 32 + kq * 8];
            accs[nt] = __builtin_amdgcn_mfma_f32_16x16x32_bf16(asl[s], brf, accs[nt], 0, 0, 0);
        }
    }
    // epilogue: C/D row = kq*4+reg, col = nt*16+m
#pragma unroll
    for (int nt = 0; nt < 4; ++nt) {
        int f = nt * 16 + m;
        float bg = b0[f], bv = bs[f];
        float g0 = bn0[f], g1 = bn0[64 + f], g2 = bn0[128 + f];
        float g3 = rsqrtf(bn0[192 + f] + EPSV);
        float s0 = bns[f], s1 = bns[64 + f], s2 = bns[128 + f];
        float s3 = rsqrtf(bns[192 + f] + EPSV);
#pragma unroll
        for (int r = 0; r < 4; ++r) {
            int v = v0 + w * 16 + kq * 4 + r;
            if (v < n) {
                float yg = fmaxf((accg[nt][r] + bg - g2) * g3 * g0 + g1, 0.0f);
                float ys = fmaxf((accs[nt][r] + bv - s2) * s3 * s0 + s1, 0.0f);
                if (outp) outp[(size_t)v * 64 + f] = packbf(yg, ys);
                if (outf) *(float2*)&outf[(size_t)v * 128 + 2 * f] = make_float2(yg, ys);
            }
        }
    }
}

// ---------------- fused dual gathers (1 wave = 1 node, lane = feature) ----------------
// L0: hb rows (128B); outputs packed (gcn|sage) uint rows.
__global__ __launch_bounds__(256) void k_gather0(const unsigned short* __restrict__ hb,
                                                 const float* __restrict__ dinv,
                                                 const float* __restrict__ cinv,
                                                 const int* __restrict__ rowptr,
                                                 const int* __restrict__ csr_src,
                                                 unsigned int* __restrict__ gb, int n) {
    int wid = threadIdx.x >> 6, lane = threadIdx.x & 63;
    int v = blockIdx.x * 4 + wid;
    if (v >= n) return;
    int beg = rowptr[v], end = rowptr[v + 1];
    float accg = 0.0f, accs = 0.0f;
    int i = beg;
    for (; i + 8 <= end; i += 8) {
        int s[8];
#pragma unroll
        for (int j = 0; j < 8; ++j) s[j] = csr_src[i + j];
        float x[8], w[8];
#pragma unroll
        for (int j = 0; j < 8; ++j) x[j] = bu2f(hb[(size_t)s[j] * 64 + lane]);
#pragma unroll
        for (int j = 0; j < 8; ++j) w[j] = dinv[s[j]];
#pragma unroll
        for (int j = 0; j < 8; ++j) { accg = fmaf(x[j], w[j], accg); accs += x[j]; }
    }
    for (; i < end; ++i) {
        int s = csr_src[i];
        float x = bu2f(hb[(size_t)s * 64 + lane]);
        accg = fmaf(x, dinv[s], accg);
        accs += x;
    }
    float dv = dinv[v];
    float yg = dv * (accg + dv * bu2f(hb[(size_t)v * 64 + lane]));
    float ys = cinv[v] * accs;
    gb[(size_t)v * 64 + lane] = packbf(yg, ys);
}

// L1: packed interleaved rows (256B); outputs packed rows.
__global__ __launch_bounds__(256) void k_gather1(const unsigned int* __restrict__ Cb,
                                                 const float* __restrict__ dinv,
                                                 const float* __restrict__ cinv,
                                                 const int* __restrict__ rowptr,
                                                 const int* __restrict__ csr_src,
                                                 unsigned int* __restrict__ gb, int n) {
    int wid = threadIdx.x >> 6, lane = threadIdx.x & 63;
    int v = blockIdx.x * 4 + wid;
    if (v >= n) return;
    int beg = rowptr[v], end = rowptr[v + 1];
    float accg = 0.0f, accs = 0.0f;
    int i = beg;
    for (; i + 8 <= end; i += 8) {
        int s[8];
#pragma unroll
        for (int j = 0; j < 8; ++j) s[j] = csr_src[i + j];
        unsigned int u[8];
#pragma unroll
        for (int j = 0; j < 8; ++j) u[j] = Cb[(size_t)s[j] * 64 + lane];
        float w[8];
#pragma unroll
        for (int j = 0; j < 8; ++j) w[j] = dinv[s[j]];
#pragma unroll
        for (int j = 0; j < 8; ++j) {
            accg = fmaf(bu2f((unsigned short)(u[j] & 0xFFFF)), w[j], accg);
            accs += bu2f((unsigned short)(u[j] >> 16));
        }
    }
    for (; i < end; ++i) {
        int s = csr_src[i];
        unsigned int u = Cb[(size_t)s * 64 + lane];
        accg = fmaf(bu2f((unsigned short)(u & 0xFFFF)), dinv[s], accg);
        accs += bu2f((unsigned short)(u >> 16));
    }
    float dv = dinv[v];
    unsigned int us = Cb[(size_t)v * 64 + lane];
    float yg = dv * (accg + dv * bu2f((unsigned short)(us & 0xFFFF)));
    float ys = cinv[v] * accs;
    gb[(size_t)v * 64 + lane] = packbf(yg, ys);
}

// ---------------- pooling over interleaved final feats ----------------
__global__ __launch_bounds__(256) void k_pool2(const float* __restrict__ X2,
                                               const int* __restrict__ batch,
                                               float* __restrict__ pooled, int n) {
    int wid = threadIdx.x >> 6, lane = threadIdx.x & 63;
    int v0 = blockIdx.x * 64 + wid * 16;
    float ag = 0.0f, as = 0.0f;
    int g = -1;
    for (int j = 0; j < 16; ++j) {
        int v = v0 + j;
        if (v >= n) break;
        int b = batch[v];
        if (b != g) {
            if (g >= 0) {
                atomicAdd(&pooled[g * 128 + lane], ag);
                atomicAdd(&pooled[g * 128 + 64 + lane], as);
            }
            g = b; ag = 0.0f; as = 0.0f;
        }
        float2 val = *(const float2*)&X2[(size_t)v * 128 + 2 * lane];
        ag += val.x; as += val.y;
    }
    if (g >= 0) {
        atomicAdd(&pooled[g * 128 + lane], ag);
        atomicAdd(&pooled[g * 128 + 64 + lane], as);
    }
}

// ---------------- head MLP (single block) ----------------
__global__ __launch_bounds__(256) void k_head(const float* __restrict__ pooled,
                                              const int* __restrict__ gcnt,
                                              const float* __restrict__ P_,
                                              const int* __restrict__ flag,
                                              void* __restrict__ out) {
    const float* f1W = P_ + PW_F1W;
    const float* f1b = P_ + PW_F1B;
    const float* bn1 = P_ + PW_BN1;
    const float* f2W = P_ + PW_F2W;
    const float* f2b = P_ + PW_F2B;
    const float* bn2 = P_ + PW_BN2;
    const float* f3W = P_ + PW_F3W;
    const float* f3b = P_ + PW_F3B;
    __shared__ float P[64][128];
    __shared__ float Z1[64][64];
    __shared__ float Z2[64][32];
    int t = threadIdx.x;
    for (int i = t; i < 64 * 128; i += 256) {
        int g = i >> 7;
        float c = fmaxf((float)gcnt[g], 1.0f);
        P[g][i & 127] = pooled[i] / c;
    }
    __syncthreads();
    for (int o = t; o < 64 * 64; o += 256) {
        int g = o >> 6, f = o & 63;
        float acc = 0.0f;
        for (int c = 0; c < 128; ++c) acc = fmaf(P[g][c], f1W[c * 64 + f], acc);
        float y = acc + f1b[f];
        y = (y - bn1[128 + f]) * rsqrtf(bn1[192 + f] + EPSV) * bn1[f] + bn1[64 + f];
        Z1[g][f] = fmaxf(y, 0.0f);
    }
    __syncthreads();
    for (int o = t; o < 64 * 32; o += 256) {
        int g = o >> 5, f = o & 31;
        float acc = 0.0f;
        for (int c = 0; c < 64; ++c) acc = fmaf(Z1[g][c], f2W[c * 32 + f], acc);
        float y = acc + f2b[f];
        y = (y - bn2[64 + f]) * rsqrtf(bn2[96 + f] + EPSV) * bn2[f] + bn2[32 + f];
        Z2[g][f] = fmaxf(y, 0.0f);
    }
    __syncthreads();
    if (t < 64) {
        float acc = 0.0f;
        for (int c = 0; c < 32; ++c) acc = fmaf(Z2[t][c], f3W[c], acc);
        float y = acc + f3b[0];
        if (*flag) ((__hip_bfloat16*)out)[t] = __float2bfloat16(y);
        else       ((float*)out)[t] = y;
    }
}

extern "C" void kernel_launch(void* const* d_in, const int* in_sizes, int n_in,
                              void* d_out, int out_size, void* d_ws, size_t ws_size,
                              hipStream_t stream) {
    (void)in_sizes; (void)n_in; (void)out_size; (void)ws_size;
    const void* x     = d_in[0];
    const int*  eidx  = (const int*)d_in[1];
    const int*  batch = (const int*)d_in[2];

    const int n = NN, E = NE;
    const int* src = eidx;
    const int* dst = eidx + E;

    char* w = (char*)d_ws;
    unsigned short* hb = (unsigned short*)w; w += (size_t)n * 64 * 2;  // bf16 h
    unsigned int* gb   = (unsigned int*)w;   w += (size_t)n * 64 * 4;  // packed gather out
    unsigned int* C1b  = (unsigned int*)w;   w += (size_t)n * 64 * 4;  // packed layer-0 out
    float* C2  = (float*)w;  w += (size_t)n * 128 * 4;                 // fp32 layer-1 out
    int*   indeg  = (int*)w;  w += (size_t)n * 4;
    int*   rowptr = (int*)w;  w += (size_t)(n + 8) * 4;
    int*   rank   = (int*)w;  w += (size_t)E * 4;
    int*   csr_src = (int*)w; w += (size_t)E * 4;
    float* dinv  = (float*)w; w += (size_t)n * 4;
    float* cinv  = (float*)w; w += (size_t)n * 4;
    int*   gcnt  = (int*)w;  w += 64 * 4;
    float* pooled = (float*)w; w += 64 * 128 * 4;
    int*   cnt   = (int*)w;  w += 8;
    int*   flag  = (int*)w;  w += 8;
    unsigned short* wt = (unsigned short*)w; w += 6 * 4096 * 2;        // bf16 W^T x6
    float* prm   = (float*)w;                                          // PW_TOT floats

    hipMemsetAsync(indeg, 0, (size_t)n * 4, stream);
    hipMemsetAsync(gcnt, 0, 64 * 4 + 64 * 128 * 4, stream);  // gcnt + pooled contiguous
    hipMemsetAsync(cnt, 0, 4, stream);

    dim3 b256(256);

    const int DETN = 262144;
    k_detect<<<dim3(DETN / 256), b256, 0, stream>>>((const unsigned short*)x, cnt, DETN);
    k_resolve<<<1, 64, 0, stream>>>(cnt, flag);
    PSrc ps;
    for (int i = 0; i < 17; ++i) ps.p[i] = d_in[3 + i];
    k_cvt<<<dim3((PW_TOT + 255) / 256), b256, 0, stream>>>(ps, flag, prm);
    k_wprep<<<dim3((6 * 4096 + 255) / 256), b256, 0, stream>>>(prm, wt);

    // CSR build (rank trick: no atomics in fill)
    k_degree<<<dim3((E + 255) / 256), b256, 0, stream>>>(dst, indeg, rank, E);
    k_scan<<<1, 1024, 0, stream>>>(indeg, rowptr, dinv, cinv, n);
    k_fill<<<dim3((E + 255) / 256), b256, 0, stream>>>(src, dst, rowptr, rank, csr_src, E);
    k_gcount<<<dim3((n + 1023) / 1024), b256, 0, stream>>>(batch, gcnt, n);

    int gGemm = (n + 63) / 64;
    int gGath = (n + 3) / 4;
    int gPool = (n + 63) / 64;

    k_in_gemm<<<gGemm, b256, 0, stream>>>(x, prm + PW_WIN, prm + PW_BIN, flag, hb, n);

    // layer 0: gather(hb) -> gb ; MFMA GEMMs -> C1b (self = hb raw ushorts)
    k_gather0<<<gGath, b256, 0, stream>>>(hb, dinv, cinv, rowptr, csr_src, gb, n);
    k_layer_mfma<<<gGemm, b256, 0, stream>>>(gb, hb, 0,
        wt + 0, wt + 4096, wt + 8192,
        prm + PW_GCNB, prm + PW_SB, prm + PW_GCNBN, prm + PW_SBN,
        (float*)nullptr, C1b, n);

    // layer 1: gather(C1b) -> gb ; MFMA GEMMs -> C2 fp32 (self = C1b hi16)
    k_gather1<<<gGath, b256, 0, stream>>>(C1b, dinv, cinv, rowptr, csr_src, gb, n);
    k_layer_mfma<<<gGemm, b256, 0, stream>>>(gb, C1b, 1,
        wt + 12288, wt + 16384, wt + 20480,
        prm + PW_GCNB + 64, prm + PW_SB + 64, prm + PW_GCNBN + 256, prm + PW_SBN + 256,
        C2, (unsigned int*)nullptr, n);

    // pooling (both halves) + head
    k_pool2<<<gPool, b256, 0, stream>>>(C2, batch, pooled, n);
    k_head<<<1, b256, 0, stream>>>(pooled, gcnt, prm, flag, d_out);
}

// Round 9
// 396.750 us; speedup vs baseline: 1.4332x; 1.1272x over previous
//
#include <hip/hip_runtime.h>
#include <hip/hip_bf16.h>

#define NN 50000
#define NE 1200000
#define DIN 128
#define HDIM 64
#define NG 64
#define EPSV 1e-5f
#define SCANBLK 1024
#define NB ((NN + SCANBLK - 1) / SCANBLK)

typedef __attribute__((ext_vector_type(8))) short bfrag;   // 8 bf16 = 4 VGPRs
typedef __attribute__((ext_vector_type(4))) float ffrag;   // 4 fp32 acc

__device__ __forceinline__ float b2f(const __hip_bfloat16 v) { return __bfloat162float(v); }
__device__ __forceinline__ float bu2f(unsigned short u) {
    return __uint_as_float(((unsigned int)u) << 16);
}
__device__ __forceinline__ unsigned short f2bu(float f) {
    __hip_bfloat16 b = __float2bfloat16(f);
    return *(unsigned short*)&b;
}
__device__ __forceinline__ unsigned int packbf(float a, float b) {
    return (unsigned int)f2bu(a) | ((unsigned int)f2bu(b) << 16);
}

__device__ __forceinline__ float ldf(const void* p, size_t idx, int isbf16) {
    return isbf16 ? b2f(((const __hip_bfloat16*)p)[idx]) : ((const float*)p)[idx];
}

// ---------------- dtype detection (flag = cnt<4 computed inline by consumers) ----------
__global__ void k_detect(const unsigned short* __restrict__ x, int* __restrict__ cnt, int n) {
    int i = blockIdx.x * 256 + threadIdx.x;
    if (i < n) {
        unsigned short u = x[i];
        if (((u >> 7) & 0xFF) == 0xFF) atomicAdd(cnt, 1);
    }
}

// ---------------- param conversion + weight transpose, one kernel ----------------
#define PW_WIN   0
#define PW_BIN   8192
#define PW_GCNW  8256
#define PW_GCNB  16448
#define PW_GCNBN 16576
#define PW_SWL   17088
#define PW_SWR   25280
#define PW_SB    33472
#define PW_SBN   33600
#define PW_F1W   34112
#define PW_F1B   42304
#define PW_BN1   42368
#define PW_F2W   42624
#define PW_F2B   44672
#define PW_BN2   44704
#define PW_F3W   44832
#define PW_F3B   44864
#define PW_TOT   44865
#define WT_TOT   (6 * 4096)

struct PSrc { const void* p[17]; };

__global__ void k_cvt(PSrc s, const int* __restrict__ cnt, float* __restrict__ dst,
                      unsigned short* __restrict__ wt) {
    const int offs[18] = {PW_WIN, PW_BIN, PW_GCNW, PW_GCNB, PW_GCNBN, PW_SWL, PW_SWR,
                          PW_SB, PW_SBN, PW_F1W, PW_F1B, PW_BN1, PW_F2W, PW_F2B,
                          PW_BN2, PW_F3W, PW_F3B, PW_TOT};
    int i = blockIdx.x * 256 + threadIdx.x;
    int f = (*cnt < 4) ? 1 : 0;
    if (i < PW_TOT) {
        int seg = 0;
        while (i >= offs[seg + 1]) ++seg;
        dst[i] = ldf(s.p[seg], i - offs[seg], f);
    } else if (i < PW_TOT + WT_TOT) {
        int j = i - PW_TOT;
        int mtx = j >> 12, idx = j & 4095;
        int nn = idx >> 6, kk = idx & 63;
        const void* wp = (mtx % 3 == 0) ? s.p[2] : (mtx % 3 == 1) ? s.p[5] : s.p[6];
        wt[j] = f2bu(ldf(wp, (size_t)(mtx / 3) * 4096 + kk * 64 + nn, f));
    }
}

// ---------------- CSR build ----------------
__global__ void k_degree(const int* __restrict__ dst, int* __restrict__ indeg,
                         int* __restrict__ rank, int E) {
    int e = blockIdx.x * 256 + threadIdx.x;
    if (e < E) rank[e] = atomicAdd(&indeg[dst[e]], 1);
}

__global__ __launch_bounds__(256) void k_gcount(const int* __restrict__ batch,
                                                int* __restrict__ gcnt, int n) {
    __shared__ int hist[NG];
    int t = threadIdx.x;
    if (t < NG) hist[t] = 0;
    __syncthreads();
    int v = blockIdx.x * 1024 + t;
#pragma unroll
    for (int j = 0; j < 4; ++j, v += 256)
        if (v < n) atomicAdd(&hist[batch[v]], 1);
    __syncthreads();
    if (t < NG) {
        int c = hist[t];
        if (c) atomicAdd(&gcnt[t], c);
    }
}

// ---- parallel 3-phase scan: local scans + block sums; scan block sums; add offsets ----
__global__ __launch_bounds__(256) void k_scan1(const int* __restrict__ indeg,
                                               int* __restrict__ rowptr,
                                               float* __restrict__ dinv,
                                               float* __restrict__ cinv,
                                               int* __restrict__ bsum, int n) {
    __shared__ int wsum[4];
    int t = threadIdx.x;
    int wid = t >> 6, lane = t & 63;
    int base = blockIdx.x * SCANBLK;
    int i0 = base + t * 4;
    int d[4];
#pragma unroll
    for (int j = 0; j < 4; ++j) {
        int i = i0 + j;
        d[j] = (i < n) ? indeg[i] : 0;
        if (i < n) {
            float fd = (float)d[j];
            dinv[i] = rsqrtf(fd + 1.0f);        // GCN deg incl. self-loop
            cinv[i] = 1.0f / fmaxf(fd, 1.0f);   // SAGE mean denom
        }
    }
    int s = d[0] + d[1] + d[2] + d[3];
    int x = s;
#pragma unroll
    for (int off = 1; off < 64; off <<= 1) {
        int y = __shfl_up(x, off, 64);
        if (lane >= off) x += y;
    }
    if (lane == 63) wsum[wid] = x;
    __syncthreads();
    int woff = 0;
#pragma unroll
    for (int j = 0; j < 4; ++j) if (j < wid) woff += wsum[j];
    int excl = woff + x - s;   // exclusive within block
    int run = 0;
#pragma unroll
    for (int j = 0; j < 4; ++j) {
        int i = i0 + j;
        if (i < n) rowptr[i] = excl + run;
        run += d[j];
    }
    if (t == 0) bsum[blockIdx.x] = wsum[0] + wsum[1] + wsum[2] + wsum[3];
}

__global__ void k_scan2(const int* __restrict__ bsum, int* __restrict__ boff,
                        int* __restrict__ rowptr, int nb, int n) {
    int lane = threadIdx.x;
    int s = (lane < nb) ? bsum[lane] : 0;
    int x = s;
#pragma unroll
    for (int off = 1; off < 64; off <<= 1) {
        int y = __shfl_up(x, off, 64);
        if (lane >= off) x += y;
    }
    if (lane < nb) boff[lane] = x - s;   // exclusive
    if (lane == nb - 1) rowptr[n] = x;   // total = E
}

__global__ void k_scan3(int* __restrict__ rowptr, const int* __restrict__ boff, int n) {
    int i = blockIdx.x * 256 + threadIdx.x;
    if (i < n) rowptr[i] += boff[i >> 10];
}

__global__ void k_fill(const int* __restrict__ src, const int* __restrict__ dst,
                       const int* __restrict__ rowptr, const int* __restrict__ rank,
                       int* __restrict__ csr_src, int E) {
    int e = blockIdx.x * 256 + threadIdx.x;
    if (e < E) {
        int d = dst[e];
        csr_src[rowptr[d] + rank[e]] = src[e];
    }
}

// ---------------- vector GEMM helper (input layer only) ----------------
__device__ __forceinline__ void mac16(float acc[4][4], const float4 av, const float4 wv) {
    float a[4] = {av.x, av.y, av.z, av.w};
    float w[4] = {wv.x, wv.y, wv.z, wv.w};
#pragma unroll
    for (int i = 0; i < 4; i++)
#pragma unroll
        for (int j = 0; j < 4; j++) acc[i][j] = fmaf(a[i], w[j], acc[i][j]);
}

// hb = bf16(relu(x @ W_in + b_in))
__global__ __launch_bounds__(256) void k_in_gemm(const void* __restrict__ A,
                                                 const float* __restrict__ W,
                                                 const float* __restrict__ bias,
                                                 const int* __restrict__ cnt,
                                                 unsigned short* __restrict__ outb, int n) {
    __shared__ float As[64][68];
    __shared__ float Ws[64][64];
    int t = threadIdx.x;
    int v0 = blockIdx.x * 64;
    int tx = t & 15, ty = t >> 4;
    int f16 = (*cnt < 4) ? 1 : 0;
    float acc[4][4] = {};
    for (int k0 = 0; k0 < 128; k0 += 64) {
#pragma unroll
        for (int j = 0; j < 16; ++j) {
            int i = t + 256 * j;
            int r = i >> 6, k = i & 63;
            int v = v0 + r;
            As[k][r] = (v < n) ? ldf(A, (size_t)v * DIN + k0 + k, f16) : 0.0f;
        }
#pragma unroll
        for (int j = 0; j < 16; ++j) {
            int i = t + 256 * j;
            Ws[i >> 6][i & 63] = W[(size_t)(k0 + (i >> 6)) * 64 + (i & 63)];
        }
        __syncthreads();
#pragma unroll 8
        for (int k = 0; k < 64; ++k) {
            float4 wv = *(const float4*)&Ws[k][tx * 4];
            float4 av = *(const float4*)&As[k][ty * 4];
            mac16(acc, av, wv);
        }
        __syncthreads();
    }
#pragma unroll
    for (int i = 0; i < 4; i++) {
        int v = v0 + ty * 4 + i;
        if (v < n) {
#pragma unroll
            for (int j = 0; j < 4; j++) {
                int f = tx * 4 + j;
                outb[(size_t)v * 64 + f] = f2bu(fmaxf(acc[i][j] + bias[f], 0.0f));
            }
        }
    }
}

// ---------------- MFMA fused layer GEMM ----------------
__global__ __launch_bounds__(256) void k_layer_mfma(
        const unsigned int* __restrict__ gb, const void* __restrict__ selfp, int selfPacked,
        const unsigned short* __restrict__ W0t, const unsigned short* __restrict__ Wlt,
        const unsigned short* __restrict__ Wrt,
        const float* __restrict__ b0, const float* __restrict__ bs,
        const float* __restrict__ bn0, const float* __restrict__ bns,
        float* __restrict__ outf, unsigned int* __restrict__ outp, int n) {
    __shared__ unsigned int Ag[64][68];
    __shared__ unsigned int Su[64][68];
    __shared__ unsigned short Wt0[64][72];
    __shared__ unsigned short Wt1[64][72];
    int t = threadIdx.x;
    int v0 = blockIdx.x * 64;

    uint4 z4 = make_uint4(0, 0, 0, 0);
#pragma unroll
    for (int j = 0; j < 4; ++j) {
        int c = t + 256 * j;
        int r = c >> 4, cq = c & 15;
        int v = v0 + r;
        uint4 val = (v < n) ? *(const uint4*)&gb[(size_t)v * 64 + cq * 4] : z4;
        *(uint4*)&Ag[r][cq * 4] = val;
    }
    if (selfPacked) {
        const unsigned int* sp = (const unsigned int*)selfp;
#pragma unroll
        for (int j = 0; j < 4; ++j) {
            int c = t + 256 * j;
            int r = c >> 4, cq = c & 15;
            int v = v0 + r;
            uint4 val = (v < n) ? *(const uint4*)&sp[(size_t)v * 64 + cq * 4] : z4;
            *(uint4*)&Su[r][cq * 4] = val;
        }
    } else {
        const unsigned int* sp = (const unsigned int*)selfp;
#pragma unroll
        for (int j = 0; j < 2; ++j) {
            int c = t + 256 * j;
            int r = c >> 3, cq = c & 7;
            int v = v0 + r;
            uint4 val = (v < n) ? *(const uint4*)&sp[(size_t)v * 32 + cq * 4] : z4;
            *(uint4*)&Su[r][cq * 4] = val;
        }
    }
#pragma unroll
    for (int j = 0; j < 2; ++j) {
        int c = t + 256 * j;
        int r = c >> 3, cq = c & 7;
        *(uint4*)&Wt0[r][cq * 8] = *(const uint4*)&W0t[r * 64 + cq * 8];
        *(uint4*)&Wt1[r][cq * 8] = *(const uint4*)&Wlt[r * 64 + cq * 8];
    }
    __syncthreads();

    int w = t >> 6, lane = t & 63;
    int m = lane & 15, kq = lane >> 4;
    int lr = w * 16 + m;

    bfrag ag[2], as_[2], asl[2];
#pragma unroll
    for (int s = 0; s < 2; ++s) {
        uint4 u0 = *(const uint4*)&Ag[lr][s * 32 + kq * 8];
        uint4 u1 = *(const uint4*)&Ag[lr][s * 32 + kq * 8 + 4];
        unsigned int uu[8] = {u0.x, u0.y, u0.z, u0.w, u1.x, u1.y, u1.z, u1.w};
#pragma unroll
        for (int j = 0; j < 8; ++j) {
            ag[s][j] = (short)(uu[j] & 0xFFFF);
            as_[s][j] = (short)(uu[j] >> 16);
        }
        if (selfPacked) {
            uint4 s0 = *(const uint4*)&Su[lr][s * 32 + kq * 8];
            uint4 s1 = *(const uint4*)&Su[lr][s * 32 + kq * 8 + 4];
            unsigned int su[8] = {s0.x, s0.y, s0.z, s0.w, s1.x, s1.y, s1.z, s1.w};
#pragma unroll
            for (int j = 0; j < 8; ++j) asl[s][j] = (short)(su[j] >> 16);
        } else {
            const unsigned short* srow = (const unsigned short*)&Su[lr][0];
            asl[s] = *(const bfrag*)(srow + s * 32 + kq * 8);
        }
    }

    ffrag zf = {0.0f, 0.0f, 0.0f, 0.0f};
    ffrag accg[4] = {zf, zf, zf, zf};
    ffrag accs[4] = {zf, zf, zf, zf};
#pragma unroll
    for (int nt = 0; nt < 4; ++nt) {
#pragma unroll
        for (int s = 0; s < 2; ++s) {
            bfrag b0f = *(const bfrag*)&Wt0[nt * 16 + m][s * 32 + kq * 8];
            accg[nt] = __builtin_amdgcn_mfma_f32_16x16x32_bf16(ag[s], b0f, accg[nt], 0, 0, 0);
            bfrag b1f = *(const bfrag*)&Wt1[nt * 16 + m][s * 32 + kq * 8];
            accs[nt] = __builtin_amdgcn_mfma_f32_16x16x32_bf16(as_[s], b1f, accs[nt], 0, 0, 0);
        }
    }
    __syncthreads();
#pragma unroll
    for (int j = 0; j < 2; ++j) {
        int c = t + 256 * j;
        int r = c >> 3, cq = c & 7;
        *(uint4*)&Wt0[r][cq * 8] = *(const uint4*)&Wrt[r * 64 + cq * 8];
    }
    __syncthreads();
#pragma unroll
    for (int nt = 0; nt < 4; ++nt) {
#pragma unroll
        for (int s = 0; s < 2; ++s) {
            bfrag brf = *(const bfrag*)&Wt0[nt * 16 + m][s * 32 + kq * 8];
            accs[nt] = __builtin_amdgcn_mfma_f32_16x16x32_bf16(asl[s], brf, accs[nt], 0, 0, 0);
        }
    }
#pragma unroll
    for (int nt = 0; nt < 4; ++nt) {
        int f = nt * 16 + m;
        float bg = b0[f], bv = bs[f];
        float g0 = bn0[f], g1 = bn0[64 + f], g2 = bn0[128 + f];
        float g3 = rsqrtf(bn0[192 + f] + EPSV);
        float s0 = bns[f], s1 = bns[64 + f], s2 = bns[128 + f];
        float s3 = rsqrtf(bns[192 + f] + EPSV);
#pragma unroll
        for (int r = 0; r < 4; ++r) {
            int v = v0 + w * 16 + kq * 4 + r;
            if (v < n) {
                float yg = fmaxf((accg[nt][r] + bg - g2) * g3 * g0 + g1, 0.0f);
                float ys = fmaxf((accs[nt][r] + bv - s2) * s3 * s0 + s1, 0.0f);
                if (outp) outp[(size_t)v * 64 + f] = packbf(yg, ys);
                if (outf) *(float2*)&outf[(size_t)v * 128 + 2 * f] = make_float2(yg, ys);
            }
        }
    }
}

// ---------------- fused dual gathers (1 wave = 1 node, lane = feature) ----------------
__global__ __launch_bounds__(256) void k_gather0(const unsigned short* __restrict__ hb,
                                                 const float* __restrict__ dinv,
                                                 const float* __restrict__ cinv,
                                                 const int* __restrict__ rowptr,
                                                 const int* __restrict__ csr_src,
                                                 unsigned int* __restrict__ gb, int n) {
    int wid = threadIdx.x >> 6, lane = threadIdx.x & 63;
    int v = blockIdx.x * 4 + wid;
    if (v >= n) return;
    int beg = rowptr[v], end = rowptr[v + 1];
    float accg = 0.0f, accs = 0.0f;
    int i = beg;
    for (; i + 8 <= end; i += 8) {
        int s[8];
#pragma unroll
        for (int j = 0; j < 8; ++j) s[j] = csr_src[i + j];
        float x[8], w[8];
#pragma unroll
        for (int j = 0; j < 8; ++j) x[j] = bu2f(hb[(size_t)s[j] * 64 + lane]);
#pragma unroll
        for (int j = 0; j < 8; ++j) w[j] = dinv[s[j]];
#pragma unroll
        for (int j = 0; j < 8; ++j) { accg = fmaf(x[j], w[j], accg); accs += x[j]; }
    }
    for (; i < end; ++i) {
        int s = csr_src[i];
        float x = bu2f(hb[(size_t)s * 64 + lane]);
        accg = fmaf(x, dinv[s], accg);
        accs += x;
    }
    float dv = dinv[v];
    float yg = dv * (accg + dv * bu2f(hb[(size_t)v * 64 + lane]));
    float ys = cinv[v] * accs;
    gb[(size_t)v * 64 + lane] = packbf(yg, ys);
}

__global__ __launch_bounds__(256) void k_gather1(const unsigned int* __restrict__ Cb,
                                                 const float* __restrict__ dinv,
                                                 const float* __restrict__ cinv,
                                                 const int* __restrict__ rowptr,
                                                 const int* __restrict__ csr_src,
                                                 unsigned int* __restrict__ gb, int n) {
    int wid = threadIdx.x >> 6, lane = threadIdx.x & 63;
    int v = blockIdx.x * 4 + wid;
    if (v >= n) return;
    int beg = rowptr[v], end = rowptr[v + 1];
    float accg = 0.0f, accs = 0.0f;
    int i = beg;
    for (; i + 8 <= end; i += 8) {
        int s[8];
#pragma unroll
        for (int j = 0; j < 8; ++j) s[j] = csr_src[i + j];
        unsigned int u[8];
#pragma unroll
        for (int j = 0; j < 8; ++j) u[j] = Cb[(size_t)s[j] * 64 + lane];
        float w[8];
#pragma unroll
        for (int j = 0; j < 8; ++j) w[j] = dinv[s[j]];
#pragma unroll
        for (int j = 0; j < 8; ++j) {
            accg = fmaf(bu2f((unsigned short)(u[j] & 0xFFFF)), w[j], accg);
            accs += bu2f((unsigned short)(u[j] >> 16));
        }
    }
    for (; i < end; ++i) {
        int s = csr_src[i];
        unsigned int u = Cb[(size_t)s * 64 + lane];
        accg = fmaf(bu2f((unsigned short)(u & 0xFFFF)), dinv[s], accg);
        accs += bu2f((unsigned short)(u >> 16));
    }
    float dv = dinv[v];
    unsigned int us = Cb[(size_t)v * 64 + lane];
    float yg = dv * (accg + dv * bu2f((unsigned short)(us & 0xFFFF)));
    float ys = cinv[v] * accs;
    gb[(size_t)v * 64 + lane] = packbf(yg, ys);
}

// ---------------- pooling over interleaved final feats ----------------
__global__ __launch_bounds__(256) void k_pool2(const float* __restrict__ X2,
                                               const int* __restrict__ batch,
                                               float* __restrict__ pooled, int n) {
    int wid = threadIdx.x >> 6, lane = threadIdx.x & 63;
    int v0 = blockIdx.x * 64 + wid * 16;
    float ag = 0.0f, as = 0.0f;
    int g = -1;
    for (int j = 0; j < 16; ++j) {
        int v = v0 + j;
        if (v >= n) break;
        int b = batch[v];
        if (b != g) {
            if (g >= 0) {
                atomicAdd(&pooled[g * 128 + lane], ag);
                atomicAdd(&pooled[g * 128 + 64 + lane], as);
            }
            g = b; ag = 0.0f; as = 0.0f;
        }
        float2 val = *(const float2*)&X2[(size_t)v * 128 + 2 * lane];
        ag += val.x; as += val.y;
    }
    if (g >= 0) {
        atomicAdd(&pooled[g * 128 + lane], ag);
        atomicAdd(&pooled[g * 128 + 64 + lane], as);
    }
}

// ---------------- head MLP (single block) ----------------
__global__ __launch_bounds__(256) void k_head(const float* __restrict__ pooled,
                                              const int* __restrict__ gcnt,
                                              const float* __restrict__ P_,
                                              const int* __restrict__ cnt,
                                              void* __restrict__ out) {
    const float* f1W = P_ + PW_F1W;
    const float* f1b = P_ + PW_F1B;
    const float* bn1 = P_ + PW_BN1;
    const float* f2W = P_ + PW_F2W;
    const float* f2b = P_ + PW_F2B;
    const float* bn2 = P_ + PW_BN2;
    const float* f3W = P_ + PW_F3W;
    const float* f3b = P_ + PW_F3B;
    __shared__ float P[64][128];
    __shared__ float Z1[64][64];
    __shared__ float Z2[64][32];
    int t = threadIdx.x;
    for (int i = t; i < 64 * 128; i += 256) {
        int g = i >> 7;
        float c = fmaxf((float)gcnt[g], 1.0f);
        P[g][i & 127] = pooled[i] / c;
    }
    __syncthreads();
    for (int o = t; o < 64 * 64; o += 256) {
        int g = o >> 6, f = o & 63;
        float acc = 0.0f;
        for (int c = 0; c < 128; ++c) acc = fmaf(P[g][c], f1W[c * 64 + f], acc);
        float y = acc + f1b[f];
        y = (y - bn1[128 + f]) * rsqrtf(bn1[192 + f] + EPSV) * bn1[f] + bn1[64 + f];
        Z1[g][f] = fmaxf(y, 0.0f);
    }
    __syncthreads();
    for (int o = t; o < 64 * 32; o += 256) {
        int g = o >> 5, f = o & 31;
        float acc = 0.0f;
        for (int c = 0; c < 64; ++c) acc = fmaf(Z1[g][c], f2W[c * 32 + f], acc);
        float y = acc + f2b[f];
        y = (y - bn2[64 + f]) * rsqrtf(bn2[96 + f] + EPSV) * bn2[f] + bn2[32 + f];
        Z2[g][f] = fmaxf(y, 0.0f);
    }
    __syncthreads();
    if (t < 64) {
        float acc = 0.0f;
        for (int c = 0; c < 32; ++c) acc = fmaf(Z2[t][c], f3W[c], acc);
        float y = acc + f3b[0];
        if (*cnt < 4) ((__hip_bfloat16*)out)[t] = __float2bfloat16(y);
        else          ((float*)out)[t] = y;
    }
}

extern "C" void kernel_launch(void* const* d_in, const int* in_sizes, int n_in,
                              void* d_out, int out_size, void* d_ws, size_t ws_size,
                              hipStream_t stream) {
    (void)in_sizes; (void)n_in; (void)out_size; (void)ws_size;
    const void* x     = d_in[0];
    const int*  eidx  = (const int*)d_in[1];
    const int*  batch = (const int*)d_in[2];

    const int n = NN, E = NE;
    const int* src = eidx;
    const int* dst = eidx + E;

    char* w = (char*)d_ws;
    // zero-init region (single memset): indeg | gcnt | pooled | cnt
    int*   indeg  = (int*)w;  w += (size_t)n * 4;
    int*   gcnt   = (int*)w;  w += 64 * 4;
    float* pooled = (float*)w; w += 64 * 128 * 4;
    int*   cnt    = (int*)w;  w += 16;
    size_t zbytes = (size_t)n * 4 + 64 * 4 + 64 * 128 * 4 + 16;
    // rest
    unsigned short* hb = (unsigned short*)w; w += (size_t)n * 64 * 2;
    unsigned int* gb   = (unsigned int*)w;   w += (size_t)n * 64 * 4;
    unsigned int* C1b  = (unsigned int*)w;   w += (size_t)n * 64 * 4;
    float* C2  = (float*)w;  w += (size_t)n * 128 * 4;
    int*   rowptr = (int*)w;  w += (size_t)(n + 8) * 4;
    int*   rank   = (int*)w;  w += (size_t)E * 4;
    int*   csr_src = (int*)w; w += (size_t)E * 4;
    float* dinv  = (float*)w; w += (size_t)n * 4;
    float* cinv  = (float*)w; w += (size_t)n * 4;
    int*   bsum  = (int*)w;  w += (NB + 8) * 4;
    int*   boff  = (int*)w;  w += (NB + 8) * 4;
    unsigned short* wt = (unsigned short*)w; w += (size_t)WT_TOT * 2;
    float* prm   = (float*)w;

    hipMemsetAsync(indeg, 0, zbytes, stream);

    dim3 b256(256);

    const int DETN = 131072;
    k_detect<<<dim3(DETN / 256), b256, 0, stream>>>((const unsigned short*)x, cnt, DETN);
    PSrc ps;
    for (int i = 0; i < 17; ++i) ps.p[i] = d_in[3 + i];
    k_cvt<<<dim3((PW_TOT + WT_TOT + 255) / 256), b256, 0, stream>>>(ps, cnt, prm, wt);

    // CSR build
    k_degree<<<dim3((E + 255) / 256), b256, 0, stream>>>(dst, indeg, rank, E);
    k_scan1<<<dim3(NB), b256, 0, stream>>>(indeg, rowptr, dinv, cinv, bsum, n);
    k_scan2<<<1, 64, 0, stream>>>(bsum, boff, rowptr, NB, n);
    k_scan3<<<dim3((n + 255) / 256), b256, 0, stream>>>(rowptr, boff, n);
    k_fill<<<dim3((E + 255) / 256), b256, 0, stream>>>(src, dst, rowptr, rank, csr_src, E);
    k_gcount<<<dim3((n + 1023) / 1024), b256, 0, stream>>>(batch, gcnt, n);

    int gGemm = (n + 63) / 64;
    int gGath = (n + 3) / 4;
    int gPool = (n + 63) / 64;

    k_in_gemm<<<gGemm, b256, 0, stream>>>(x, prm + PW_WIN, prm + PW_BIN, cnt, hb, n);

    // layer 0
    k_gather0<<<gGath, b256, 0, stream>>>(hb, dinv, cinv, rowptr, csr_src, gb, n);
    k_layer_mfma<<<gGemm, b256, 0, stream>>>(gb, hb, 0,
        wt + 0, wt + 4096, wt + 8192,
        prm + PW_GCNB, prm + PW_SB, prm + PW_GCNBN, prm + PW_SBN,
        (float*)nullptr, C1b, n);

    // layer 1
    k_gather1<<<gGath, b256, 0, stream>>>(C1b, dinv, cinv, rowptr, csr_src, gb, n);
    k_layer_mfma<<<gGemm, b256, 0, stream>>>(gb, C1b, 1,
        wt + 12288, wt + 16384, wt + 20480,
        prm + PW_GCNB + 64, prm + PW_SB + 64, prm + PW_GCNBN + 256, prm + PW_SBN + 256,
        C2, (unsigned int*)nullptr, n);

    // pooling + head
    k_pool2<<<gPool, b256, 0, stream>>>(C2, batch, pooled, n);
    k_head<<<1, b256, 0, stream>>>(pooled, gcnt, prm, cnt, d_out);
}

// Round 10
// 373.132 us; speedup vs baseline: 1.5239x; 1.0633x over previous
//
#include <hip/hip_runtime.h>
#include <hip/hip_bf16.h>

#define NN 50000
#define NE 1200000
#define DIN 128
#define HDIM 64
#define NG 64
#define EPSV 1e-5f
#define SCANBLK 1024
#define NB ((NN + SCANBLK - 1) / SCANBLK)

typedef __attribute__((ext_vector_type(8))) short bfrag;   // 8 bf16 = 4 VGPRs
typedef __attribute__((ext_vector_type(4))) float ffrag;   // 4 fp32 acc

__device__ __forceinline__ float b2f(const __hip_bfloat16 v) { return __bfloat162float(v); }
__device__ __forceinline__ float bu2f(unsigned short u) {
    return __uint_as_float(((unsigned int)u) << 16);
}
__device__ __forceinline__ unsigned short f2bu(float f) {
    __hip_bfloat16 b = __float2bfloat16(f);
    return *(unsigned short*)&b;
}
__device__ __forceinline__ unsigned int packbf(float a, float b) {
    return (unsigned int)f2bu(a) | ((unsigned int)f2bu(b) << 16);
}

__device__ __forceinline__ float ldf(const void* p, size_t idx, int isbf16) {
    return isbf16 ? b2f(((const __hip_bfloat16*)p)[idx]) : ((const float*)p)[idx];
}

// ---------------- dtype detection (flag = cnt<4 computed inline by consumers) ----------
__global__ void k_detect(const unsigned short* __restrict__ x, int* __restrict__ cnt, int n) {
    int i = blockIdx.x * 256 + threadIdx.x;
    if (i < n) {
        unsigned short u = x[i];
        if (((u >> 7) & 0xFF) == 0xFF) atomicAdd(cnt, 1);
    }
}

// ---------------- param conversion + weight transposes, one kernel ----------------
#define PW_WIN   0
#define PW_BIN   8192
#define PW_GCNW  8256
#define PW_GCNB  16448
#define PW_GCNBN 16576
#define PW_SWL   17088
#define PW_SWR   25280
#define PW_SB    33472
#define PW_SBN   33600
#define PW_F1W   34112
#define PW_F1B   42304
#define PW_BN1   42368
#define PW_F2W   42624
#define PW_F2B   44672
#define PW_BN2   44704
#define PW_F3W   44832
#define PW_F3B   44864
#define PW_TOT   44865
#define WT_TOT   (6 * 4096)
#define WIN_TOT  8192

struct PSrc { const void* p[17]; };

__global__ void k_cvt(PSrc s, const int* __restrict__ cnt, float* __restrict__ dst,
                      unsigned short* __restrict__ wt) {
    const int offs[18] = {PW_WIN, PW_BIN, PW_GCNW, PW_GCNB, PW_GCNBN, PW_SWL, PW_SWR,
                          PW_SB, PW_SBN, PW_F1W, PW_F1B, PW_BN1, PW_F2W, PW_F2B,
                          PW_BN2, PW_F3W, PW_F3B, PW_TOT};
    int i = blockIdx.x * 256 + threadIdx.x;
    int f = (*cnt < 4) ? 1 : 0;
    if (i < PW_TOT) {
        int seg = 0;
        while (i >= offs[seg + 1]) ++seg;
        dst[i] = ldf(s.p[seg], i - offs[seg], f);
    } else if (i < PW_TOT + WT_TOT) {
        int j = i - PW_TOT;
        int mtx = j >> 12, idx = j & 4095;
        int nn = idx >> 6, kk = idx & 63;
        const void* wp = (mtx % 3 == 0) ? s.p[2] : (mtx % 3 == 1) ? s.p[5] : s.p[6];
        wt[j] = f2bu(ldf(wp, (size_t)(mtx / 3) * 4096 + kk * 64 + nn, f));
    } else if (i < PW_TOT + WT_TOT + WIN_TOT) {
        int idx = i - PW_TOT - WT_TOT;
        int nn = idx >> 7, kk = idx & 127;     // WinT[nn][kk] = W_in[kk][nn]
        wt[WT_TOT + idx] = f2bu(ldf(s.p[0], (size_t)kk * 64 + nn, f));
    }
}

// ---------------- CSR build ----------------
__global__ void k_degree(const int* __restrict__ dst, int* __restrict__ indeg,
                         int* __restrict__ rank, int E) {
    int e = blockIdx.x * 256 + threadIdx.x;
    if (e < E) rank[e] = atomicAdd(&indeg[dst[e]], 1);
}

__global__ __launch_bounds__(256) void k_gcount(const int* __restrict__ batch,
                                                int* __restrict__ gcnt, int n) {
    __shared__ int hist[NG];
    int t = threadIdx.x;
    if (t < NG) hist[t] = 0;
    __syncthreads();
    int v = blockIdx.x * 1024 + t;
#pragma unroll
    for (int j = 0; j < 4; ++j, v += 256)
        if (v < n) atomicAdd(&hist[batch[v]], 1);
    __syncthreads();
    if (t < NG) {
        int c = hist[t];
        if (c) atomicAdd(&gcnt[t], c);
    }
}

// ---- parallel 3-phase scan ----
__global__ __launch_bounds__(256) void k_scan1(const int* __restrict__ indeg,
                                               int* __restrict__ rowptr,
                                               float* __restrict__ dinv,
                                               float* __restrict__ cinv,
                                               int* __restrict__ bsum, int n) {
    __shared__ int wsum[4];
    int t = threadIdx.x;
    int wid = t >> 6, lane = t & 63;
    int base = blockIdx.x * SCANBLK;
    int i0 = base + t * 4;
    int d[4];
#pragma unroll
    for (int j = 0; j < 4; ++j) {
        int i = i0 + j;
        d[j] = (i < n) ? indeg[i] : 0;
        if (i < n) {
            float fd = (float)d[j];
            dinv[i] = rsqrtf(fd + 1.0f);
            cinv[i] = 1.0f / fmaxf(fd, 1.0f);
        }
    }
    int s = d[0] + d[1] + d[2] + d[3];
    int x = s;
#pragma unroll
    for (int off = 1; off < 64; off <<= 1) {
        int y = __shfl_up(x, off, 64);
        if (lane >= off) x += y;
    }
    if (lane == 63) wsum[wid] = x;
    __syncthreads();
    int woff = 0;
#pragma unroll
    for (int j = 0; j < 4; ++j) if (j < wid) woff += wsum[j];
    int excl = woff + x - s;
    int run = 0;
#pragma unroll
    for (int j = 0; j < 4; ++j) {
        int i = i0 + j;
        if (i < n) rowptr[i] = excl + run;
        run += d[j];
    }
    if (t == 0) bsum[blockIdx.x] = wsum[0] + wsum[1] + wsum[2] + wsum[3];
}

__global__ void k_scan2(const int* __restrict__ bsum, int* __restrict__ boff,
                        int* __restrict__ rowptr, int nb, int n) {
    int lane = threadIdx.x;
    int s = (lane < nb) ? bsum[lane] : 0;
    int x = s;
#pragma unroll
    for (int off = 1; off < 64; off <<= 1) {
        int y = __shfl_up(x, off, 64);
        if (lane >= off) x += y;
    }
    if (lane < nb) boff[lane] = x - s;
    if (lane == nb - 1) rowptr[n] = x;
}

__global__ void k_scan3(int* __restrict__ rowptr, const int* __restrict__ boff, int n) {
    int i = blockIdx.x * 256 + threadIdx.x;
    if (i < n) rowptr[i] += boff[i >> 10];
}

__global__ void k_fill(const int* __restrict__ src, const int* __restrict__ dst,
                       const int* __restrict__ rowptr, const int* __restrict__ rank,
                       int* __restrict__ csr_src, int E) {
    int e = blockIdx.x * 256 + threadIdx.x;
    if (e < E) {
        int d = dst[e];
        csr_src[rowptr[d] + rank[e]] = src[e];
    }
}

// ---------------- MFMA input GEMM: hb = bf16(relu(x @ W_in + b_in)) ----------------
__global__ __launch_bounds__(256) void k_in_mfma(const void* __restrict__ A,
                                                 const unsigned short* __restrict__ WinT,
                                                 const float* __restrict__ bias,
                                                 const int* __restrict__ cnt,
                                                 unsigned short* __restrict__ outb, int n) {
    __shared__ unsigned short Xs[64][136];
    __shared__ unsigned short Wt[64][136];
    int t = threadIdx.x;
    int v0 = blockIdx.x * 64;
    int f16 = (*cnt < 4) ? 1 : 0;
#pragma unroll
    for (int j = 0; j < 32; ++j) {
        int i = t + 256 * j;
        int r = i >> 7, c = i & 127;
        int v = v0 + r;
        Xs[r][c] = (v < n) ? f2bu(ldf(A, (size_t)v * DIN + c, f16)) : 0;
    }
#pragma unroll
    for (int j = 0; j < 4; ++j) {
        int c = t + 256 * j;
        int r = c >> 4, cq = c & 15;
        *(uint4*)&Wt[r][cq * 8] = *(const uint4*)&WinT[r * 128 + cq * 8];
    }
    __syncthreads();
    int w = t >> 6, lane = t & 63;
    int m = lane & 15, kq = lane >> 4;
    int lr = w * 16 + m;
    bfrag a[4];
#pragma unroll
    for (int s = 0; s < 4; ++s) a[s] = *(const bfrag*)&Xs[lr][s * 32 + kq * 8];
    ffrag zf = {0.0f, 0.0f, 0.0f, 0.0f};
    ffrag acc[4] = {zf, zf, zf, zf};
#pragma unroll
    for (int nt = 0; nt < 4; ++nt)
#pragma unroll
        for (int s = 0; s < 4; ++s) {
            bfrag b = *(const bfrag*)&Wt[nt * 16 + m][s * 32 + kq * 8];
            acc[nt] = __builtin_amdgcn_mfma_f32_16x16x32_bf16(a[s], b, acc[nt], 0, 0, 0);
        }
#pragma unroll
    for (int nt = 0; nt < 4; ++nt) {
        int f = nt * 16 + m;
        float bb = bias[f];
#pragma unroll
        for (int r = 0; r < 4; ++r) {
            int v = v0 + w * 16 + kq * 4 + r;
            if (v < n) outb[(size_t)v * 64 + f] = f2bu(fmaxf(acc[nt][r] + bb, 0.0f));
        }
    }
}

// ---------------- MFMA fused layer GEMM ----------------
__global__ __launch_bounds__(256) void k_layer_mfma(
        const unsigned int* __restrict__ gb, const void* __restrict__ selfp, int selfPacked,
        const unsigned short* __restrict__ W0t, const unsigned short* __restrict__ Wlt,
        const unsigned short* __restrict__ Wrt,
        const float* __restrict__ b0, const float* __restrict__ bs,
        const float* __restrict__ bn0, const float* __restrict__ bns,
        float* __restrict__ outf, unsigned int* __restrict__ outp, int n) {
    __shared__ unsigned int Ag[64][68];
    __shared__ unsigned int Su[64][68];
    __shared__ unsigned short Wt0[64][72];
    __shared__ unsigned short Wt1[64][72];
    int t = threadIdx.x;
    int v0 = blockIdx.x * 64;

    uint4 z4 = make_uint4(0, 0, 0, 0);
#pragma unroll
    for (int j = 0; j < 4; ++j) {
        int c = t + 256 * j;
        int r = c >> 4, cq = c & 15;
        int v = v0 + r;
        uint4 val = (v < n) ? *(const uint4*)&gb[(size_t)v * 64 + cq * 4] : z4;
        *(uint4*)&Ag[r][cq * 4] = val;
    }
    if (selfPacked) {
        const unsigned int* sp = (const unsigned int*)selfp;
#pragma unroll
        for (int j = 0; j < 4; ++j) {
            int c = t + 256 * j;
            int r = c >> 4, cq = c & 15;
            int v = v0 + r;
            uint4 val = (v < n) ? *(const uint4*)&sp[(size_t)v * 64 + cq * 4] : z4;
            *(uint4*)&Su[r][cq * 4] = val;
        }
    } else {
        const unsigned int* sp = (const unsigned int*)selfp;
#pragma unroll
        for (int j = 0; j < 2; ++j) {
            int c = t + 256 * j;
            int r = c >> 3, cq = c & 7;
            int v = v0 + r;
            uint4 val = (v < n) ? *(const uint4*)&sp[(size_t)v * 32 + cq * 4] : z4;
            *(uint4*)&Su[r][cq * 4] = val;
        }
    }
#pragma unroll
    for (int j = 0; j < 2; ++j) {
        int c = t + 256 * j;
        int r = c >> 3, cq = c & 7;
        *(uint4*)&Wt0[r][cq * 8] = *(const uint4*)&W0t[r * 64 + cq * 8];
        *(uint4*)&Wt1[r][cq * 8] = *(const uint4*)&Wlt[r * 64 + cq * 8];
    }
    __syncthreads();

    int w = t >> 6, lane = t & 63;
    int m = lane & 15, kq = lane >> 4;
    int lr = w * 16 + m;

    bfrag ag[2], as_[2], asl[2];
#pragma unroll
    for (int s = 0; s < 2; ++s) {
        uint4 u0 = *(const uint4*)&Ag[lr][s * 32 + kq * 8];
        uint4 u1 = *(const uint4*)&Ag[lr][s * 32 + kq * 8 + 4];
        unsigned int uu[8] = {u0.x, u0.y, u0.z, u0.w, u1.x, u1.y, u1.z, u1.w};
#pragma unroll
        for (int j = 0; j < 8; ++j) {
            ag[s][j] = (short)(uu[j] & 0xFFFF);
            as_[s][j] = (short)(uu[j] >> 16);
        }
        if (selfPacked) {
            uint4 s0 = *(const uint4*)&Su[lr][s * 32 + kq * 8];
            uint4 s1 = *(const uint4*)&Su[lr][s * 32 + kq * 8 + 4];
            unsigned int su[8] = {s0.x, s0.y, s0.z, s0.w, s1.x, s1.y, s1.z, s1.w};
#pragma unroll
            for (int j = 0; j < 8; ++j) asl[s][j] = (short)(su[j] >> 16);
        } else {
            const unsigned short* srow = (const unsigned short*)&Su[lr][0];
            asl[s] = *(const bfrag*)(srow + s * 32 + kq * 8);
        }
    }

    ffrag zf = {0.0f, 0.0f, 0.0f, 0.0f};
    ffrag accg[4] = {zf, zf, zf, zf};
    ffrag accs[4] = {zf, zf, zf, zf};
#pragma unroll
    for (int nt = 0; nt < 4; ++nt) {
#pragma unroll
        for (int s = 0; s < 2; ++s) {
            bfrag b0f = *(const bfrag*)&Wt0[nt * 16 + m][s * 32 + kq * 8];
            accg[nt] = __builtin_amdgcn_mfma_f32_16x16x32_bf16(ag[s], b0f, accg[nt], 0, 0, 0);
            bfrag b1f = *(const bfrag*)&Wt1[nt * 16 + m][s * 32 + kq * 8];
            accs[nt] = __builtin_amdgcn_mfma_f32_16x16x32_bf16(as_[s], b1f, accs[nt], 0, 0, 0);
        }
    }
    __syncthreads();
#pragma unroll
    for (int j = 0; j < 2; ++j) {
        int c = t + 256 * j;
        int r = c >> 3, cq = c & 7;
        *(uint4*)&Wt0[r][cq * 8] = *(const uint4*)&Wrt[r * 64 + cq * 8];
    }
    __syncthreads();
#pragma unroll
    for (int nt = 0; nt < 4; ++nt) {
#pragma unroll
        for (int s = 0; s < 2; ++s) {
            bfrag brf = *(const bfrag*)&Wt0[nt * 16 + m][s * 32 + kq * 8];
            accs[nt] = __builtin_amdgcn_mfma_f32_16x16x32_bf16(asl[s], brf, accs[nt], 0, 0, 0);
        }
    }
#pragma unroll
    for (int nt = 0; nt < 4; ++nt) {
        int f = nt * 16 + m;
        float bg = b0[f], bv = bs[f];
        float g0 = bn0[f], g1 = bn0[64 + f], g2 = bn0[128 + f];
        float g3 = rsqrtf(bn0[192 + f] + EPSV);
        float s0 = bns[f], s1 = bns[64 + f], s2 = bns[128 + f];
        float s3 = rsqrtf(bns[192 + f] + EPSV);
#pragma unroll
        for (int r = 0; r < 4; ++r) {
            int v = v0 + w * 16 + kq * 4 + r;
            if (v < n) {
                float yg = fmaxf((accg[nt][r] + bg - g2) * g3 * g0 + g1, 0.0f);
                float ys = fmaxf((accs[nt][r] + bv - s2) * s3 * s0 + s1, 0.0f);
                if (outp) outp[(size_t)v * 64 + f] = packbf(yg, ys);
                if (outf) *(float2*)&outf[(size_t)v * 128 + 2 * f] = make_float2(yg, ys);
            }
        }
    }
}

// ------- quarter-wave dual gathers: 16 lanes = 1 edge, 4 features/lane -------
// L0: hb rows (128B, ushort). Lane covers feats 4ql..4ql+3 via one uint2 load.
__global__ __launch_bounds__(256) void k_gather0(const unsigned short* __restrict__ hb,
                                                 const float* __restrict__ dinv,
                                                 const float* __restrict__ cinv,
                                                 const int* __restrict__ rowptr,
                                                 const int* __restrict__ csr_src,
                                                 unsigned int* __restrict__ gb, int n) {
    int wid = threadIdx.x >> 6, lane = threadIdx.x & 63;
    int v = blockIdx.x * 4 + wid;
    if (v >= n) return;
    int q = lane >> 4, ql = lane & 15;
    int beg = rowptr[v], end = rowptr[v + 1];
    float accg[4] = {0, 0, 0, 0}, accs[4] = {0, 0, 0, 0};
    int i = beg;
    for (; i + 8 <= end; i += 8) {
        int s0 = csr_src[i + q];
        int s1 = csr_src[i + 4 + q];
        uint2 u0 = *(const uint2*)&hb[(size_t)s0 * 64 + ql * 4];
        uint2 u1 = *(const uint2*)&hb[(size_t)s1 * 64 + ql * 4];
        float w0 = dinv[s0], w1 = dinv[s1];
        float x0[4] = {bu2f((unsigned short)(u0.x & 0xFFFF)), bu2f((unsigned short)(u0.x >> 16)),
                       bu2f((unsigned short)(u0.y & 0xFFFF)), bu2f((unsigned short)(u0.y >> 16))};
        float x1[4] = {bu2f((unsigned short)(u1.x & 0xFFFF)), bu2f((unsigned short)(u1.x >> 16)),
                       bu2f((unsigned short)(u1.y & 0xFFFF)), bu2f((unsigned short)(u1.y >> 16))};
#pragma unroll
        for (int k = 0; k < 4; ++k) {
            accg[k] = fmaf(x0[k], w0, accg[k]); accs[k] += x0[k];
            accg[k] = fmaf(x1[k], w1, accg[k]); accs[k] += x1[k];
        }
    }
    for (; i < end; i += 4) {
        int e = i + q;
        if (e < end) {
            int s = csr_src[e];
            uint2 u = *(const uint2*)&hb[(size_t)s * 64 + ql * 4];
            float w = dinv[s];
            float x[4] = {bu2f((unsigned short)(u.x & 0xFFFF)), bu2f((unsigned short)(u.x >> 16)),
                          bu2f((unsigned short)(u.y & 0xFFFF)), bu2f((unsigned short)(u.y >> 16))};
#pragma unroll
            for (int k = 0; k < 4; ++k) { accg[k] = fmaf(x[k], w, accg[k]); accs[k] += x[k]; }
        }
    }
#pragma unroll
    for (int k = 0; k < 4; ++k) {
        accg[k] += __shfl_xor(accg[k], 16, 64);
        accg[k] += __shfl_xor(accg[k], 32, 64);
        accs[k] += __shfl_xor(accs[k], 16, 64);
        accs[k] += __shfl_xor(accs[k], 32, 64);
    }
    if (q == 0) {
        float dv = dinv[v], cv = cinv[v];
        uint2 us = *(const uint2*)&hb[(size_t)v * 64 + ql * 4];
        float sx[4] = {bu2f((unsigned short)(us.x & 0xFFFF)), bu2f((unsigned short)(us.x >> 16)),
                       bu2f((unsigned short)(us.y & 0xFFFF)), bu2f((unsigned short)(us.y >> 16))};
        unsigned int pk[4];
#pragma unroll
        for (int k = 0; k < 4; ++k) {
            float yg = dv * (accg[k] + dv * sx[k]);
            float ys = cv * accs[k];
            pk[k] = packbf(yg, ys);
        }
        *(uint4*)&gb[(size_t)v * 64 + ql * 4] = make_uint4(pk[0], pk[1], pk[2], pk[3]);
    }
}

// L1: packed rows (256B, uint). Lane covers feats 4ql..4ql+3 via one uint4 load.
__global__ __launch_bounds__(256) void k_gather1(const unsigned int* __restrict__ Cb,
                                                 const float* __restrict__ dinv,
                                                 const float* __restrict__ cinv,
                                                 const int* __restrict__ rowptr,
                                                 const int* __restrict__ csr_src,
                                                 unsigned int* __restrict__ gb, int n) {
    int wid = threadIdx.x >> 6, lane = threadIdx.x & 63;
    int v = blockIdx.x * 4 + wid;
    if (v >= n) return;
    int q = lane >> 4, ql = lane & 15;
    int beg = rowptr[v], end = rowptr[v + 1];
    float accg[4] = {0, 0, 0, 0}, accs[4] = {0, 0, 0, 0};
    int i = beg;
    for (; i + 8 <= end; i += 8) {
        int s0 = csr_src[i + q];
        int s1 = csr_src[i + 4 + q];
        uint4 u0 = *(const uint4*)&Cb[(size_t)s0 * 64 + ql * 4];
        uint4 u1 = *(const uint4*)&Cb[(size_t)s1 * 64 + ql * 4];
        float w0 = dinv[s0], w1 = dinv[s1];
        unsigned int a0[4] = {u0.x, u0.y, u0.z, u0.w};
        unsigned int a1[4] = {u1.x, u1.y, u1.z, u1.w};
#pragma unroll
        for (int k = 0; k < 4; ++k) {
            accg[k] = fmaf(bu2f((unsigned short)(a0[k] & 0xFFFF)), w0, accg[k]);
            accs[k] += bu2f((unsigned short)(a0[k] >> 16));
            accg[k] = fmaf(bu2f((unsigned short)(a1[k] & 0xFFFF)), w1, accg[k]);
            accs[k] += bu2f((unsigned short)(a1[k] >> 16));
        }
    }
    for (; i < end; i += 4) {
        int e = i + q;
        if (e < end) {
            int s = csr_src[e];
            uint4 u = *(const uint4*)&Cb[(size_t)s * 64 + ql * 4];
            float w = dinv[s];
            unsigned int a[4] = {u.x, u.y, u.z, u.w};
#pragma unroll
            for (int k = 0; k < 4; ++k) {
                accg[k] = fmaf(bu2f((unsigned short)(a[k] & 0xFFFF)), w, accg[k]);
                accs[k] += bu2f((unsigned short)(a[k] >> 16));
            }
        }
    }
#pragma unroll
    for (int k = 0; k < 4; ++k) {
        accg[k] += __shfl_xor(accg[k], 16, 64);
        accg[k] += __shfl_xor(accg[k], 32, 64);
        accs[k] += __shfl_xor(accs[k], 16, 64);
        accs[k] += __shfl_xor(accs[k], 32, 64);
    }
    if (q == 0) {
        float dv = dinv[v], cv = cinv[v];
        uint4 us = *(const uint4*)&Cb[(size_t)v * 64 + ql * 4];
        unsigned int su[4] = {us.x, us.y, us.z, us.w};
        unsigned int pk[4];
#pragma unroll
        for (int k = 0; k < 4; ++k) {
            float yg = dv * (accg[k] + dv * bu2f((unsigned short)(su[k] & 0xFFFF)));
            float ys = cv * accs[k];
            pk[k] = packbf(yg, ys);
        }
        *(uint4*)&gb[(size_t)v * 64 + ql * 4] = make_uint4(pk[0], pk[1], pk[2], pk[3]);
    }
}

// ---------------- pooling over interleaved final feats ----------------
__global__ __launch_bounds__(256) void k_pool2(const float* __restrict__ X2,
                                               const int* __restrict__ batch,
                                               float* __restrict__ pooled, int n) {
    int wid = threadIdx.x >> 6, lane = threadIdx.x & 63;
    int v0 = blockIdx.x * 64 + wid * 16;
    float ag = 0.0f, as = 0.0f;
    int g = -1;
    for (int j = 0; j < 16; ++j) {
        int v = v0 + j;
        if (v >= n) break;
        int b = batch[v];
        if (b != g) {
            if (g >= 0) {
                atomicAdd(&pooled[g * 128 + lane], ag);
                atomicAdd(&pooled[g * 128 + 64 + lane], as);
            }
            g = b; ag = 0.0f; as = 0.0f;
        }
        float2 val = *(const float2*)&X2[(size_t)v * 128 + 2 * lane];
        ag += val.x; as += val.y;
    }
    if (g >= 0) {
        atomicAdd(&pooled[g * 128 + lane], ag);
        atomicAdd(&pooled[g * 128 + 64 + lane], as);
    }
}

// ---------------- head MLP (single block) ----------------
__global__ __launch_bounds__(256) void k_head(const float* __restrict__ pooled,
                                              const int* __restrict__ gcnt,
                                              const float* __restrict__ P_,
                                              const int* __restrict__ cnt,
                                              void* __restrict__ out) {
    const float* f1W = P_ + PW_F1W;
    const float* f1b = P_ + PW_F1B;
    const float* bn1 = P_ + PW_BN1;
    const float* f2W = P_ + PW_F2W;
    const float* f2b = P_ + PW_F2B;
    const float* bn2 = P_ + PW_BN2;
    const float* f3W = P_ + PW_F3W;
    const float* f3b = P_ + PW_F3B;
    __shared__ float P[64][128];
    __shared__ float Z1[64][64];
    __shared__ float Z2[64][32];
    int t = threadIdx.x;
    for (int i = t; i < 64 * 128; i += 256) {
        int g = i >> 7;
        float c = fmaxf((float)gcnt[g], 1.0f);
        P[g][i & 127] = pooled[i] / c;
    }
    __syncthreads();
    for (int o = t; o < 64 * 64; o += 256) {
        int g = o >> 6, f = o & 63;
        float acc = 0.0f;
        for (int c = 0; c < 128; ++c) acc = fmaf(P[g][c], f1W[c * 64 + f], acc);
        float y = acc + f1b[f];
        y = (y - bn1[128 + f]) * rsqrtf(bn1[192 + f] + EPSV) * bn1[f] + bn1[64 + f];
        Z1[g][f] = fmaxf(y, 0.0f);
    }
    __syncthreads();
    for (int o = t; o < 64 * 32; o += 256) {
        int g = o >> 5, f = o & 31;
        float acc = 0.0f;
        for (int c = 0; c < 64; ++c) acc = fmaf(Z1[g][c], f2W[c * 32 + f], acc);
        float y = acc + f2b[f];
        y = (y - bn2[64 + f]) * rsqrtf(bn2[96 + f] + EPSV) * bn2[f] + bn2[32 + f];
        Z2[g][f] = fmaxf(y, 0.0f);
    }
    __syncthreads();
    if (t < 64) {
        float acc = 0.0f;
        for (int c = 0; c < 32; ++c) acc = fmaf(Z2[t][c], f3W[c], acc);
        float y = acc + f3b[0];
        if (*cnt < 4) ((__hip_bfloat16*)out)[t] = __float2bfloat16(y);
        else          ((float*)out)[t] = y;
    }
}

extern "C" void kernel_launch(void* const* d_in, const int* in_sizes, int n_in,
                              void* d_out, int out_size, void* d_ws, size_t ws_size,
                              hipStream_t stream) {
    (void)in_sizes; (void)n_in; (void)out_size; (void)ws_size;
    const void* x     = d_in[0];
    const int*  eidx  = (const int*)d_in[1];
    const int*  batch = (const int*)d_in[2];

    const int n = NN, E = NE;
    const int* src = eidx;
    const int* dst = eidx + E;

    char* w = (char*)d_ws;
    // zero-init region (single memset): indeg | gcnt | pooled | cnt
    int*   indeg  = (int*)w;  w += (size_t)n * 4;
    int*   gcnt   = (int*)w;  w += 64 * 4;
    float* pooled = (float*)w; w += 64 * 128 * 4;
    int*   cnt    = (int*)w;  w += 16;
    size_t zbytes = (size_t)n * 4 + 64 * 4 + 64 * 128 * 4 + 16;
    // rest
    unsigned short* hb = (unsigned short*)w; w += (size_t)n * 64 * 2;
    unsigned int* gb   = (unsigned int*)w;   w += (size_t)n * 64 * 4;
    unsigned int* C1b  = (unsigned int*)w;   w += (size_t)n * 64 * 4;
    float* C2  = (float*)w;  w += (size_t)n * 128 * 4;
    int*   rowptr = (int*)w;  w += (size_t)(n + 8) * 4;
    int*   rank   = (int*)w;  w += (size_t)E * 4;
    int*   csr_src = (int*)w; w += (size_t)E * 4;
    float* dinv  = (float*)w; w += (size_t)n * 4;
    float* cinv  = (float*)w; w += (size_t)n * 4;
    int*   bsum  = (int*)w;  w += (NB + 8) * 4;
    int*   boff  = (int*)w;  w += (NB + 8) * 4;
    unsigned short* wt = (unsigned short*)w; w += (size_t)(WT_TOT + WIN_TOT) * 2;
    float* prm   = (float*)w;

    hipMemsetAsync(indeg, 0, zbytes, stream);

    dim3 b256(256);

    const int DETN = 131072;
    k_detect<<<dim3(DETN / 256), b256, 0, stream>>>((const unsigned short*)x, cnt, DETN);
    PSrc ps;
    for (int i = 0; i < 17; ++i) ps.p[i] = d_in[3 + i];
    k_cvt<<<dim3((PW_TOT + WT_TOT + WIN_TOT + 255) / 256), b256, 0, stream>>>(ps, cnt, prm, wt);

    // CSR build
    k_degree<<<dim3((E + 255) / 256), b256, 0, stream>>>(dst, indeg, rank, E);
    k_scan1<<<dim3(NB), b256, 0, stream>>>(indeg, rowptr, dinv, cinv, bsum, n);
    k_scan2<<<1, 64, 0, stream>>>(bsum, boff, rowptr, NB, n);
    k_scan3<<<dim3((n + 255) / 256), b256, 0, stream>>>(rowptr, boff, n);
    k_fill<<<dim3((E + 255) / 256), b256, 0, stream>>>(src, dst, rowptr, rank, csr_src, E);
    k_gcount<<<dim3((n + 1023) / 1024), b256, 0, stream>>>(batch, gcnt, n);

    int gGemm = (n + 63) / 64;
    int gGath = (n + 3) / 4;
    int gPool = (n + 63) / 64;

    k_in_mfma<<<gGemm, b256, 0, stream>>>(x, wt + WT_TOT, prm + PW_BIN, cnt, hb, n);

    // layer 0
    k_gather0<<<gGath, b256, 0, stream>>>(hb, dinv, cinv, rowptr, csr_src, gb, n);
    k_layer_mfma<<<gGemm, b256, 0, stream>>>(gb, hb, 0,
        wt + 0, wt + 4096, wt + 8192,
        prm + PW_GCNB, prm + PW_SB, prm + PW_GCNBN, prm + PW_SBN,
        (float*)nullptr, C1b, n);

    // layer 1
    k_gather1<<<gGath, b256, 0, stream>>>(C1b, dinv, cinv, rowptr, csr_src, gb, n);
    k_layer_mfma<<<gGemm, b256, 0, stream>>>(gb, C1b, 1,
        wt + 12288, wt + 16384, wt + 20480,
        prm + PW_GCNB + 64, prm + PW_SB + 64, prm + PW_GCNBN + 256, prm + PW_SBN + 256,
        C2, (unsigned int*)nullptr, n);

    // pooling + head
    k_pool2<<<gPool, b256, 0, stream>>>(C2, batch, pooled, n);
    k_head<<<1, b256, 0, stream>>>(pooled, gcnt, prm, cnt, d_out);
}